// Round 2
// baseline (1466.625 us; speedup 1.0000x reference)
//
#include <hip/hip_runtime.h>
#include <hip/hip_bf16.h>

typedef __hip_bfloat16 bf16;

// ---- degree count (self-loop added as +1 in k_dinv) ----
__global__ __launch_bounds__(256) void k_deg(const int* __restrict__ col, int E,
                                             unsigned* __restrict__ deg) {
  int e = blockIdx.x * 256 + threadIdx.x;
  if (e < E) atomicAdd(&deg[col[e]], 1u);
}

__global__ __launch_bounds__(256) void k_dinv(const unsigned* __restrict__ deg,
                                              float* __restrict__ dinv, int n) {
  int i = blockIdx.x * 256 + threadIdx.x;
  if (i < n) dinv[i] = rsqrtf((float)deg[i] + 1.0f);  // +1 = self-loop
}

// ---- h1[n,64] = x[n,128] @ W1[128,64], fp32 in, bf16 out ----
__global__ __launch_bounds__(256) void k_gemm1(const float* __restrict__ x,
                                               const float* __restrict__ W,
                                               bf16* __restrict__ h, int n) {
  __shared__ float Ws[128 * 64];   // 32 KB
  __shared__ float xs[4 * 128];    // 2 KB
  int tid = threadIdx.x;
  for (int i = tid; i < 128 * 64 / 4; i += 256)
    ((float4*)Ws)[i] = ((const float4*)W)[i];
  long r0 = (long)blockIdx.x * 4;
  if (r0 * 128 + 512 <= (long)n * 128) {
    const float4* xsrc = (const float4*)(x + r0 * 128);
    for (int i = tid; i < 128; i += 256) ((float4*)xs)[i] = xsrc[i];
  } else {
    for (int i = tid; i < 512; i += 256) {
      long idx = r0 * 128 + i;
      xs[i] = (idx < (long)n * 128) ? x[idx] : 0.f;
    }
  }
  __syncthreads();
  int c = tid & 63, rr = tid >> 6;
  int r = (int)r0 + rr;
  if (r >= n) return;
  const float* xr = &xs[rr * 128];
  float a0 = 0.f, a1 = 0.f, a2 = 0.f, a3 = 0.f;
#pragma unroll
  for (int k = 0; k < 128; k += 4) {
    a0 = fmaf(xr[k + 0], Ws[(k + 0) * 64 + c], a0);
    a1 = fmaf(xr[k + 1], Ws[(k + 1) * 64 + c], a1);
    a2 = fmaf(xr[k + 2], Ws[(k + 2) * 64 + c], a2);
    a3 = fmaf(xr[k + 3], Ws[(k + 3) * 64 + c], a3);
  }
  h[r * 64 + c] = __float2bfloat16((a0 + a1) + (a2 + a3));
}

// ---- out1[i,l] = dinv[i]^2 * h1[i,l] + b1[l]  (self-loop + bias) ----
__global__ __launch_bounds__(256) void k_init1(const bf16* __restrict__ h1,
                                               const float* __restrict__ dinv,
                                               const float* __restrict__ b1,
                                               float* __restrict__ out1, int n) {
  int idx = blockIdx.x * 256 + threadIdx.x;
  if (idx < n * 64) {
    int i = idx >> 6, l = idx & 63;
    float d = dinv[i];
    out1[idx] = d * d * __bfloat162float(h1[idx]) + b1[l];
  }
}

// ---- conv1 scatter: one 64-lane wave per edge ----
__global__ __launch_bounds__(256) void k_agg1(const int* __restrict__ row,
                                              const int* __restrict__ col,
                                              const float* __restrict__ dinv,
                                              const bf16* __restrict__ h1,
                                              float* __restrict__ out1, int E) {
  int lane = threadIdx.x & 63;
  int e = blockIdx.x * 4 + (threadIdx.x >> 6);
  if (e >= E) return;
  int r = row[e], c = col[e];
  float w = dinv[r] * dinv[c];
  unsafeAtomicAdd(&out1[c * 64 + lane], w * __bfloat162float(h1[r * 64 + lane]));
}

// ---- h2[n,32] = relu(z1[n,64]) @ W2[64,32], fp32 ----
__global__ __launch_bounds__(256) void k_gemm2(const float* __restrict__ z1,
                                               const float* __restrict__ W,
                                               float* __restrict__ h, int n) {
  __shared__ float Ws[64 * 32];   // 8 KB
  __shared__ float zs[8 * 64];    // 2 KB
  int tid = threadIdx.x;
  for (int i = tid; i < 64 * 32 / 4; i += 256)
    ((float4*)Ws)[i] = ((const float4*)W)[i];
  long r0 = (long)blockIdx.x * 8;
  for (int i = tid; i < 8 * 64; i += 256) {
    long idx = r0 * 64 + i;
    zs[i] = (idx < (long)n * 64) ? fmaxf(z1[idx], 0.f) : 0.f;  // relu folded
  }
  __syncthreads();
  int c = tid & 31, rr = tid >> 5;
  int r = (int)r0 + rr;
  if (r >= n) return;
  const float* zr = &zs[rr * 64];
  float a0 = 0.f, a1 = 0.f, a2 = 0.f, a3 = 0.f;
#pragma unroll
  for (int k = 0; k < 64; k += 4) {
    a0 = fmaf(zr[k + 0], Ws[(k + 0) * 32 + c], a0);
    a1 = fmaf(zr[k + 1], Ws[(k + 1) * 32 + c], a1);
    a2 = fmaf(zr[k + 2], Ws[(k + 2) * 32 + c], a2);
    a3 = fmaf(zr[k + 3], Ws[(k + 3) * 32 + c], a3);
  }
  h[r * 32 + c] = (a0 + a1) + (a2 + a3);
}

// ---- z2[i,l] = dinv[i]^2 * h2[i,l] + b2[l] ----
__global__ __launch_bounds__(256) void k_init2(const float* __restrict__ h2,
                                               const float* __restrict__ dinv,
                                               const float* __restrict__ b2,
                                               float* __restrict__ z2, int n) {
  int idx = blockIdx.x * 256 + threadIdx.x;
  if (idx < n * 32) {
    int i = idx >> 5, l = idx & 31;
    float d = dinv[i];
    z2[idx] = d * d * h2[idx] + b2[l];
  }
}

// ---- conv2 scatter: half-wave (32 lanes) per edge ----
__global__ __launch_bounds__(256) void k_agg2(const int* __restrict__ row,
                                              const int* __restrict__ col,
                                              const float* __restrict__ dinv,
                                              const float* __restrict__ h2,
                                              float* __restrict__ z2, int E) {
  int lane = threadIdx.x & 31;
  int e = blockIdx.x * 8 + (threadIdx.x >> 5);
  if (e >= E) return;
  int r = row[e], c = col[e];
  float w = dinv[r] * dinv[c];
  unsafeAtomicAdd(&z2[c * 32 + lane], w * h2[r * 32 + lane]);
}

// ---- link decode: half-wave per label edge, shuffle reduce, fp32 out ----
__global__ __launch_bounds__(256) void k_decode(const int* __restrict__ ea,
                                                const int* __restrict__ eb,
                                                const float* __restrict__ z2,
                                                float* __restrict__ out, int EL) {
  int lane = threadIdx.x & 31;
  int e = blockIdx.x * 8 + (threadIdx.x >> 5);
  if (e >= EL) return;
  int a = ea[e], b = eb[e];
  float p = z2[a * 32 + lane] * z2[b * 32 + lane];
  p += __shfl_down(p, 16);
  p += __shfl_down(p, 8);
  p += __shfl_down(p, 4);
  p += __shfl_down(p, 2);
  p += __shfl_down(p, 1);
  if (lane == 0) out[e] = p;
}

extern "C" void kernel_launch(void* const* d_in, const int* in_sizes, int n_in,
                              void* d_out, int out_size, void* d_ws, size_t ws_size,
                              hipStream_t stream) {
  const float* x   = (const float*)d_in[0];
  const float* W1  = (const float*)d_in[1];
  const float* b1  = (const float*)d_in[2];
  const float* W2  = (const float*)d_in[3];
  const float* b2  = (const float*)d_in[4];
  const int*   ei  = (const int*)d_in[5];   // [2,E]: row=ei[0..E), col=ei[E..2E)
  const int*   eli = (const int*)d_in[6];   // [2,EL]

  const int N  = in_sizes[0] / 128;  // 100000
  const int E  = in_sizes[5] / 2;    // 3200000
  const int EL = in_sizes[6] / 2;    // 200000
  const int* row = ei;
  const int* col = ei + E;

  // workspace (peak ~39.2 MB):
  //   deg u32[N] | dinv f32[N] | bufH: h1 bf16[N*64] later h2 f32[N*32] (12.8MB)
  //   | bufZ: out1/z1 f32[N*64], later z2 f32[N*32] aliases its front (25.6MB)
  char* ws = (char*)d_ws;
  size_t off = 0;
  auto take = [&](size_t bytes) { char* p = ws + off; off += (bytes + 255) & ~(size_t)255; return p; };
  unsigned* deg  = (unsigned*)take((size_t)N * 4);
  float*    dinv = (float*)take((size_t)N * 4);
  char*     bufH = take((size_t)N * 64 * 2);      // h1 bf16 / h2 f32 (same 12.8MB)
  float*    bufZ = (float*)take((size_t)N * 64 * 4);
  (void)ws_size; (void)n_in; (void)out_size;

  bf16*  h1 = (bf16*)bufH;
  float* h2 = (float*)bufH;   // aliases h1 (h1 dead when h2 written)
  float* z1 = bufZ;           // out1 == z1
  float* z2 = bufZ;           // aliases z1 front half (z1 dead when z2 written)

  hipMemsetAsync(deg, 0, (size_t)N * 4, stream);
  k_deg  <<<(E + 255) / 256, 256, 0, stream>>>(col, E, deg);
  k_dinv <<<(N + 255) / 256, 256, 0, stream>>>(deg, dinv, N);

  k_gemm1<<<(N + 3) / 4, 256, 0, stream>>>(x, W1, h1, N);
  k_init1<<<(N * 64 + 255) / 256, 256, 0, stream>>>(h1, dinv, b1, z1, N);
  k_agg1 <<<(E + 3) / 4, 256, 0, stream>>>(row, col, dinv, h1, z1, E);

  k_gemm2<<<(N + 7) / 8, 256, 0, stream>>>(z1, W2, h2, N);
  k_init2<<<(N * 32 + 255) / 256, 256, 0, stream>>>(h2, dinv, b2, z2, N);
  k_agg2 <<<(E + 7) / 8, 256, 0, stream>>>(row, col, dinv, h2, z2, E);

  k_decode<<<(EL + 7) / 8, 256, 0, stream>>>(eli, eli + EL, z2, (float*)d_out, EL);
}

// Round 3
// 902.537 us; speedup vs baseline: 1.6250x; 1.6250x over previous
//
#include <hip/hip_runtime.h>
#include <hip/hip_bf16.h>

typedef __hip_bfloat16 bf16;

__device__ __forceinline__ float ldval(float v) { return v; }
__device__ __forceinline__ float ldval(bf16 v) { return __bfloat162float(v); }

// ---- degree count (self-loop added as +1 in k_dinv) ----
__global__ __launch_bounds__(256) void k_deg(const int* __restrict__ col, int E,
                                             unsigned* __restrict__ deg) {
  int e = blockIdx.x * 256 + threadIdx.x;
  if (e < E) atomicAdd(&deg[col[e]], 1u);
}

__global__ __launch_bounds__(256) void k_dinv(const unsigned* __restrict__ deg,
                                              float* __restrict__ dinv, int n) {
  int i = blockIdx.x * 256 + threadIdx.x;
  if (i < n) dinv[i] = rsqrtf((float)deg[i] + 1.0f);  // +1 = self-loop
}

// ---- single-block exclusive scan of deg -> row_start[N+1], cursor[N] ----
__global__ __launch_bounds__(1024) void k_scan(const unsigned* __restrict__ deg, int n,
                                               int* __restrict__ row_start,
                                               int* __restrict__ cursor) {
  __shared__ int part[1024];
  int tid = threadIdx.x;
  int chunk = (n + 1023) >> 10;
  int lo = tid * chunk;
  int hi = min(lo + chunk, n);
  int s = 0;
  for (int i = lo; i < hi; i++) s += (int)deg[i];
  part[tid] = s;
  __syncthreads();
  for (int d = 1; d < 1024; d <<= 1) {   // Hillis-Steele inclusive scan
    int v = (tid >= d) ? part[tid - d] : 0;
    __syncthreads();
    part[tid] += v;
    __syncthreads();
  }
  int off = (tid == 0) ? 0 : part[tid - 1];  // exclusive prefix
  for (int i = lo; i < hi; i++) {
    row_start[i] = off;
    cursor[i] = off;
    off += (int)deg[i];
  }
  if (tid == 1023) row_start[n] = off;  // == E (works even if this thread's range is empty)
}

// ---- counting-sort scatter: adj[pos] = {src_row, norm_weight} sorted by dest col ----
__global__ __launch_bounds__(256) void k_scatter(const int* __restrict__ row,
                                                 const int* __restrict__ col,
                                                 const float* __restrict__ dinv, int E,
                                                 int* __restrict__ cursor,
                                                 int2* __restrict__ adj) {
  int e = blockIdx.x * 256 + threadIdx.x;
  if (e >= E) return;
  int r = row[e], c = col[e];
  int pos = atomicAdd(&cursor[c], 1);
  float w = dinv[r] * dinv[c];
  adj[pos] = make_int2(r, __float_as_int(w));
}

// ---- h1[n,64] = x[n,128] @ W1[128,64], fp32 in, bf16 out ----
__global__ __launch_bounds__(256) void k_gemm1(const float* __restrict__ x,
                                               const float* __restrict__ W,
                                               bf16* __restrict__ h, int n) {
  __shared__ float Ws[128 * 64];   // 32 KB
  __shared__ float xs[4 * 128];    // 2 KB
  int tid = threadIdx.x;
  for (int i = tid; i < 128 * 64 / 4; i += 256)
    ((float4*)Ws)[i] = ((const float4*)W)[i];
  long r0 = (long)blockIdx.x * 4;
  if (r0 * 128 + 512 <= (long)n * 128) {
    const float4* xsrc = (const float4*)(x + r0 * 128);
    for (int i = tid; i < 128; i += 256) ((float4*)xs)[i] = xsrc[i];
  } else {
    for (int i = tid; i < 512; i += 256) {
      long idx = r0 * 128 + i;
      xs[i] = (idx < (long)n * 128) ? x[idx] : 0.f;
    }
  }
  __syncthreads();
  int c = tid & 63, rr = tid >> 6;
  int r = (int)r0 + rr;
  if (r >= n) return;
  const float* xr = &xs[rr * 128];
  float a0 = 0.f, a1 = 0.f, a2 = 0.f, a3 = 0.f;
#pragma unroll
  for (int k = 0; k < 128; k += 4) {
    a0 = fmaf(xr[k + 0], Ws[(k + 0) * 64 + c], a0);
    a1 = fmaf(xr[k + 1], Ws[(k + 1) * 64 + c], a1);
    a2 = fmaf(xr[k + 2], Ws[(k + 2) * 64 + c], a2);
    a3 = fmaf(xr[k + 3], Ws[(k + 3) * 64 + c], a3);
  }
  h[r * 64 + c] = __float2bfloat16((a0 + a1) + (a2 + a3));
}

// ---- CSR gather-aggregate, fused self-loop + bias init ----
// F lanes per dest node; z[c,:] = sum_e w_e * h[r_e,:] + dinv[c]^2 * h[c,:] + bias
template <int F, typename T>
__global__ __launch_bounds__(256) void k_gagg(const int* __restrict__ row_start,
                                              const int2* __restrict__ adj,
                                              const float* __restrict__ dinv,
                                              const T* __restrict__ h,
                                              const float* __restrict__ bias,
                                              float* __restrict__ z, int n) {
  constexpr int PER = 256 / F;
  int lane = threadIdx.x & (F - 1);
  int c = blockIdx.x * PER + (threadIdx.x / F);
  if (c >= n) return;
  float d = dinv[c];
  float acc = fmaf(d * d, ldval(h[(long)c * F + lane]), bias[lane]);
  int j = row_start[c];
  int end = row_start[c + 1];
  for (; j + 4 <= end; j += 4) {
    int2 e0 = adj[j], e1 = adj[j + 1], e2 = adj[j + 2], e3 = adj[j + 3];
    float v0 = ldval(h[(long)e0.x * F + lane]);
    float v1 = ldval(h[(long)e1.x * F + lane]);
    float v2 = ldval(h[(long)e2.x * F + lane]);
    float v3 = ldval(h[(long)e3.x * F + lane]);
    acc = fmaf(__int_as_float(e0.y), v0, acc);
    acc = fmaf(__int_as_float(e1.y), v1, acc);
    acc = fmaf(__int_as_float(e2.y), v2, acc);
    acc = fmaf(__int_as_float(e3.y), v3, acc);
  }
  for (; j < end; j++) {
    int2 e = adj[j];
    acc = fmaf(__int_as_float(e.y), ldval(h[(long)e.x * F + lane]), acc);
  }
  z[(long)c * F + lane] = acc;
}

// ---- h2[n,32] = relu(z1[n,64]) @ W2[64,32], fp32 ----
__global__ __launch_bounds__(256) void k_gemm2(const float* __restrict__ z1,
                                               const float* __restrict__ W,
                                               float* __restrict__ h, int n) {
  __shared__ float Ws[64 * 32];   // 8 KB
  __shared__ float zs[8 * 64];    // 2 KB
  int tid = threadIdx.x;
  for (int i = tid; i < 64 * 32 / 4; i += 256)
    ((float4*)Ws)[i] = ((const float4*)W)[i];
  long r0 = (long)blockIdx.x * 8;
  for (int i = tid; i < 8 * 64; i += 256) {
    long idx = r0 * 64 + i;
    zs[i] = (idx < (long)n * 64) ? fmaxf(z1[idx], 0.f) : 0.f;  // relu folded
  }
  __syncthreads();
  int c = tid & 31, rr = tid >> 5;
  int r = (int)r0 + rr;
  if (r >= n) return;
  const float* zr = &zs[rr * 64];
  float a0 = 0.f, a1 = 0.f, a2 = 0.f, a3 = 0.f;
#pragma unroll
  for (int k = 0; k < 64; k += 4) {
    a0 = fmaf(zr[k + 0], Ws[(k + 0) * 32 + c], a0);
    a1 = fmaf(zr[k + 1], Ws[(k + 1) * 32 + c], a1);
    a2 = fmaf(zr[k + 2], Ws[(k + 2) * 32 + c], a2);
    a3 = fmaf(zr[k + 3], Ws[(k + 3) * 32 + c], a3);
  }
  h[r * 32 + c] = (a0 + a1) + (a2 + a3);
}

// ---- link decode: half-wave per label edge, shuffle reduce, fp32 out ----
__global__ __launch_bounds__(256) void k_decode(const int* __restrict__ ea,
                                                const int* __restrict__ eb,
                                                const float* __restrict__ z2,
                                                float* __restrict__ out, int EL) {
  int lane = threadIdx.x & 31;
  int e = blockIdx.x * 8 + (threadIdx.x >> 5);
  if (e >= EL) return;
  int a = ea[e], b = eb[e];
  float p = z2[a * 32 + lane] * z2[b * 32 + lane];
  p += __shfl_down(p, 16);
  p += __shfl_down(p, 8);
  p += __shfl_down(p, 4);
  p += __shfl_down(p, 2);
  p += __shfl_down(p, 1);
  if (lane == 0) out[e] = p;
}

extern "C" void kernel_launch(void* const* d_in, const int* in_sizes, int n_in,
                              void* d_out, int out_size, void* d_ws, size_t ws_size,
                              hipStream_t stream) {
  const float* x   = (const float*)d_in[0];
  const float* W1  = (const float*)d_in[1];
  const float* b1  = (const float*)d_in[2];
  const float* W2  = (const float*)d_in[3];
  const float* b2  = (const float*)d_in[4];
  const int*   ei  = (const int*)d_in[5];   // [2,E]: row=ei[0..E), col=ei[E..2E)
  const int*   eli = (const int*)d_in[6];   // [2,EL]

  const int N  = in_sizes[0] / 128;  // 100000
  const int E  = in_sizes[5] / 2;    // 3200000
  const int EL = in_sizes[6] / 2;    // 200000
  const int* row = ei;
  const int* col = ei + E;

  // workspace (~66 MB): deg u32[N] | dinv f32[N] | row_start i32[N+1] | cursor i32[N]
  //   | adj int2[E] (25.6MB) | bufH: h1 bf16[N*64] / h2 f32[N*32] (12.8MB)
  //   | bufZ: z1 f32[N*64] (25.6MB), z2 f32[N*32] aliases front
  char* ws = (char*)d_ws;
  size_t off = 0;
  auto take = [&](size_t bytes) { char* p = ws + off; off += (bytes + 255) & ~(size_t)255; return p; };
  unsigned* deg       = (unsigned*)take((size_t)N * 4);
  float*    dinv      = (float*)take((size_t)N * 4);
  int*      row_start = (int*)take((size_t)(N + 1) * 4);
  int*      cursor    = (int*)take((size_t)N * 4);
  int2*     adj       = (int2*)take((size_t)E * 8);
  char*     bufH      = take((size_t)N * 64 * 2);
  float*    bufZ      = (float*)take((size_t)N * 64 * 4);
  (void)ws_size; (void)n_in; (void)out_size;

  bf16*  h1 = (bf16*)bufH;
  float* h2 = (float*)bufH;   // aliases h1 (h1 dead when h2 written)
  float* z1 = bufZ;
  float* z2 = bufZ;           // aliases z1 front half (z1 dead when z2 written)

  hipMemsetAsync(deg, 0, (size_t)N * 4, stream);
  k_deg    <<<(E + 255) / 256, 256, 0, stream>>>(col, E, deg);
  k_dinv   <<<(N + 255) / 256, 256, 0, stream>>>(deg, dinv, N);
  k_scan   <<<1, 1024, 0, stream>>>(deg, N, row_start, cursor);
  k_scatter<<<(E + 255) / 256, 256, 0, stream>>>(row, col, dinv, E, cursor, adj);

  k_gemm1<<<(N + 3) / 4, 256, 0, stream>>>(x, W1, h1, N);
  k_gagg<64, bf16><<<(N + 3) / 4, 256, 0, stream>>>(row_start, adj, dinv, h1, b1, z1, N);

  k_gemm2<<<(N + 7) / 8, 256, 0, stream>>>(z1, W2, h2, N);
  k_gagg<32, float><<<(N + 7) / 8, 256, 0, stream>>>(row_start, adj, dinv, h2, b2, z2, N);

  k_decode<<<(EL + 7) / 8, 256, 0, stream>>>(eli, eli + EL, z2, (float*)d_out, EL);
}

// Round 4
// 691.069 us; speedup vs baseline: 2.1223x; 1.3060x over previous
//
#include <hip/hip_runtime.h>
#include <hip/hip_bf16.h>

typedef __hip_bfloat16 bf16;

__device__ __forceinline__ float ldval(float v) { return v; }
__device__ __forceinline__ float ldval(bf16 v) { return __bfloat162float(v); }

#define SCAN_BLK 2048  // 256 threads x 8 elements

// ---- degree count (self-loop added as +1 in k_dinv) ----
__global__ __launch_bounds__(256) void k_deg(const int* __restrict__ col, int E,
                                             unsigned* __restrict__ deg) {
  int e = blockIdx.x * 256 + threadIdx.x;
  if (e < E) atomicAdd(&deg[col[e]], 1u);
}

__global__ __launch_bounds__(256) void k_dinv(const unsigned* __restrict__ deg,
                                              float* __restrict__ dinv, int n) {
  int i = blockIdx.x * 256 + threadIdx.x;
  if (i < n) dinv[i] = rsqrtf((float)deg[i] + 1.0f);  // +1 = self-loop
}

// ---- scan phase 1: per-block (2048-chunk) sums ----
__global__ __launch_bounds__(256) void k_part(const unsigned* __restrict__ deg, int n,
                                              int* __restrict__ part) {
  __shared__ int sm[256];
  int t = threadIdx.x;
  int base = blockIdx.x * SCAN_BLK + t * 8;
  int s = 0;
#pragma unroll
  for (int i = 0; i < 8; i++) {
    int idx = base + i;
    if (idx < n) s += (int)deg[idx];
  }
  sm[t] = s;
  __syncthreads();
  for (int d = 128; d > 0; d >>= 1) {
    if (t < d) sm[t] += sm[t + d];
    __syncthreads();
  }
  if (t == 0) part[blockIdx.x] = sm[0];
}

// ---- scan phase 2: exclusive-scan the partials (tiny) ----
__global__ __launch_bounds__(64) void k_scanpart(int* __restrict__ part, int nb,
                                                 int* __restrict__ row_start, int n) {
  if (threadIdx.x == 0) {
    int off = 0;
    for (int b = 0; b < nb; b++) { int v = part[b]; part[b] = off; off += v; }
    row_start[n] = off;  // == E
  }
}

// ---- scan phase 3: block-local exclusive scan + global offset ----
__global__ __launch_bounds__(256) void k_rowstart(const unsigned* __restrict__ deg, int n,
                                                  const int* __restrict__ part,
                                                  int* __restrict__ row_start,
                                                  int* __restrict__ cursor) {
  __shared__ int sm[256];
  int t = threadIdx.x;
  int base = blockIdx.x * SCAN_BLK + t * 8;
  int v[8];
  int s = 0;
#pragma unroll
  for (int i = 0; i < 8; i++) {
    int idx = base + i;
    v[i] = (idx < n) ? (int)deg[idx] : 0;
    s += v[i];
  }
  sm[t] = s;
  __syncthreads();
  for (int d = 1; d < 256; d <<= 1) {   // Hillis-Steele inclusive
    int x = (t >= d) ? sm[t - d] : 0;
    __syncthreads();
    sm[t] += x;
    __syncthreads();
  }
  int off = part[blockIdx.x] + ((t == 0) ? 0 : sm[t - 1]);
#pragma unroll
  for (int i = 0; i < 8; i++) {
    int idx = base + i;
    if (idx < n) { row_start[idx] = off; cursor[idx] = off; off += v[i]; }
  }
}

// ---- counting-sort scatter: adj[pos] = {src_row, norm_weight} sorted by dest col ----
__global__ __launch_bounds__(256) void k_scatter(const int* __restrict__ row,
                                                 const int* __restrict__ col,
                                                 const float* __restrict__ dinv, int E,
                                                 int* __restrict__ cursor,
                                                 int2* __restrict__ adj) {
  int e = blockIdx.x * 256 + threadIdx.x;
  if (e >= E) return;
  int r = row[e], c = col[e];
  int pos = atomicAdd(&cursor[c], 1);
  float w = dinv[r] * dinv[c];
  adj[pos] = make_int2(r, __float_as_int(w));
}

// ---- h1[n,64] = x[n,128] @ W1[128,64], fp32 in, bf16 out ----
__global__ __launch_bounds__(256) void k_gemm1(const float* __restrict__ x,
                                               const float* __restrict__ W,
                                               bf16* __restrict__ h, int n) {
  __shared__ float Ws[128 * 64];   // 32 KB
  __shared__ float xs[4 * 128];    // 2 KB
  int tid = threadIdx.x;
  for (int i = tid; i < 128 * 64 / 4; i += 256)
    ((float4*)Ws)[i] = ((const float4*)W)[i];
  long r0 = (long)blockIdx.x * 4;
  if (r0 * 128 + 512 <= (long)n * 128) {
    const float4* xsrc = (const float4*)(x + r0 * 128);
    for (int i = tid; i < 128; i += 256) ((float4*)xs)[i] = xsrc[i];
  } else {
    for (int i = tid; i < 512; i += 256) {
      long idx = r0 * 128 + i;
      xs[i] = (idx < (long)n * 128) ? x[idx] : 0.f;
    }
  }
  __syncthreads();
  int c = tid & 63, rr = tid >> 6;
  int r = (int)r0 + rr;
  if (r >= n) return;
  const float* xr = &xs[rr * 128];
  float a0 = 0.f, a1 = 0.f, a2 = 0.f, a3 = 0.f;
#pragma unroll
  for (int k = 0; k < 128; k += 4) {
    a0 = fmaf(xr[k + 0], Ws[(k + 0) * 64 + c], a0);
    a1 = fmaf(xr[k + 1], Ws[(k + 1) * 64 + c], a1);
    a2 = fmaf(xr[k + 2], Ws[(k + 2) * 64 + c], a2);
    a3 = fmaf(xr[k + 3], Ws[(k + 3) * 64 + c], a3);
  }
  h[r * 64 + c] = __float2bfloat16((a0 + a1) + (a2 + a3));
}

// ---- CSR gather-aggregate, fused self-loop + bias init ----
template <int F, typename T>
__global__ __launch_bounds__(256) void k_gagg(const int* __restrict__ row_start,
                                              const int2* __restrict__ adj,
                                              const float* __restrict__ dinv,
                                              const T* __restrict__ h,
                                              const float* __restrict__ bias,
                                              float* __restrict__ z, int n) {
  constexpr int PER = 256 / F;
  int lane = threadIdx.x & (F - 1);
  int c = blockIdx.x * PER + (threadIdx.x / F);
  if (c >= n) return;
  float d = dinv[c];
  float acc = fmaf(d * d, ldval(h[(long)c * F + lane]), bias[lane]);
  int j = row_start[c];
  int end = row_start[c + 1];
  for (; j + 4 <= end; j += 4) {
    int2 e0 = adj[j], e1 = adj[j + 1], e2 = adj[j + 2], e3 = adj[j + 3];
    float v0 = ldval(h[(long)e0.x * F + lane]);
    float v1 = ldval(h[(long)e1.x * F + lane]);
    float v2 = ldval(h[(long)e2.x * F + lane]);
    float v3 = ldval(h[(long)e3.x * F + lane]);
    acc = fmaf(__int_as_float(e0.y), v0, acc);
    acc = fmaf(__int_as_float(e1.y), v1, acc);
    acc = fmaf(__int_as_float(e2.y), v2, acc);
    acc = fmaf(__int_as_float(e3.y), v3, acc);
  }
  for (; j < end; j++) {
    int2 e = adj[j];
    acc = fmaf(__int_as_float(e.y), ldval(h[(long)e.x * F + lane]), acc);
  }
  z[(long)c * F + lane] = acc;
}

// ---- h2[n,32] = relu(z1[n,64]) @ W2[64,32], fp32 ----
__global__ __launch_bounds__(256) void k_gemm2(const float* __restrict__ z1,
                                               const float* __restrict__ W,
                                               float* __restrict__ h, int n) {
  __shared__ float Ws[64 * 32];   // 8 KB
  __shared__ float zs[8 * 64];    // 2 KB
  int tid = threadIdx.x;
  for (int i = tid; i < 64 * 32 / 4; i += 256)
    ((float4*)Ws)[i] = ((const float4*)W)[i];
  long r0 = (long)blockIdx.x * 8;
  for (int i = tid; i < 8 * 64; i += 256) {
    long idx = r0 * 64 + i;
    zs[i] = (idx < (long)n * 64) ? fmaxf(z1[idx], 0.f) : 0.f;  // relu folded
  }
  __syncthreads();
  int c = tid & 31, rr = tid >> 5;
  int r = (int)r0 + rr;
  if (r >= n) return;
  const float* zr = &zs[rr * 64];
  float a0 = 0.f, a1 = 0.f, a2 = 0.f, a3 = 0.f;
#pragma unroll
  for (int k = 0; k < 64; k += 4) {
    a0 = fmaf(zr[k + 0], Ws[(k + 0) * 32 + c], a0);
    a1 = fmaf(zr[k + 1], Ws[(k + 1) * 32 + c], a1);
    a2 = fmaf(zr[k + 2], Ws[(k + 2) * 32 + c], a2);
    a3 = fmaf(zr[k + 3], Ws[(k + 3) * 32 + c], a3);
  }
  h[r * 32 + c] = (a0 + a1) + (a2 + a3);
}

// ---- link decode: half-wave per label edge, shuffle reduce, fp32 out ----
__global__ __launch_bounds__(256) void k_decode(const int* __restrict__ ea,
                                                const int* __restrict__ eb,
                                                const float* __restrict__ z2,
                                                float* __restrict__ out, int EL) {
  int lane = threadIdx.x & 31;
  int e = blockIdx.x * 8 + (threadIdx.x >> 5);
  if (e >= EL) return;
  int a = ea[e], b = eb[e];
  float p = z2[a * 32 + lane] * z2[b * 32 + lane];
  p += __shfl_down(p, 16);
  p += __shfl_down(p, 8);
  p += __shfl_down(p, 4);
  p += __shfl_down(p, 2);
  p += __shfl_down(p, 1);
  if (lane == 0) out[e] = p;
}

extern "C" void kernel_launch(void* const* d_in, const int* in_sizes, int n_in,
                              void* d_out, int out_size, void* d_ws, size_t ws_size,
                              hipStream_t stream) {
  const float* x   = (const float*)d_in[0];
  const float* W1  = (const float*)d_in[1];
  const float* b1  = (const float*)d_in[2];
  const float* W2  = (const float*)d_in[3];
  const float* b2  = (const float*)d_in[4];
  const int*   ei  = (const int*)d_in[5];   // [2,E]: row=ei[0..E), col=ei[E..2E)
  const int*   eli = (const int*)d_in[6];   // [2,EL]

  const int N  = in_sizes[0] / 128;  // 100000
  const int E  = in_sizes[5] / 2;    // 3200000
  const int EL = in_sizes[6] / 2;    // 200000
  const int* row = ei;
  const int* col = ei + E;
  const int NB = (N + SCAN_BLK - 1) / SCAN_BLK;  // 49

  // workspace (~66 MB)
  char* ws = (char*)d_ws;
  size_t off = 0;
  auto take = [&](size_t bytes) { char* p = ws + off; off += (bytes + 255) & ~(size_t)255; return p; };
  unsigned* deg       = (unsigned*)take((size_t)N * 4);
  float*    dinv      = (float*)take((size_t)N * 4);
  int*      row_start = (int*)take((size_t)(N + 1) * 4);
  int*      cursor    = (int*)take((size_t)N * 4);
  int*      part      = (int*)take((size_t)NB * 4);
  int2*     adj       = (int2*)take((size_t)E * 8);
  char*     bufH      = take((size_t)N * 64 * 2);
  float*    bufZ      = (float*)take((size_t)N * 64 * 4);
  (void)ws_size; (void)n_in; (void)out_size;

  bf16*  h1 = (bf16*)bufH;
  float* h2 = (float*)bufH;   // aliases h1 (h1 dead when h2 written)
  float* z1 = bufZ;
  float* z2 = bufZ;           // aliases z1 front half (z1 dead when z2 written)

  hipMemsetAsync(deg, 0, (size_t)N * 4, stream);
  k_deg     <<<(E + 255) / 256, 256, 0, stream>>>(col, E, deg);
  k_dinv    <<<(N + 255) / 256, 256, 0, stream>>>(deg, dinv, N);
  k_part    <<<NB, 256, 0, stream>>>(deg, N, part);
  k_scanpart<<<1, 64, 0, stream>>>(part, NB, row_start, N);
  k_rowstart<<<NB, 256, 0, stream>>>(deg, N, part, row_start, cursor);
  k_scatter <<<(E + 255) / 256, 256, 0, stream>>>(row, col, dinv, E, cursor, adj);

  k_gemm1<<<(N + 3) / 4, 256, 0, stream>>>(x, W1, h1, N);
  k_gagg<64, bf16><<<(N + 3) / 4, 256, 0, stream>>>(row_start, adj, dinv, h1, b1, z1, N);

  k_gemm2<<<(N + 7) / 8, 256, 0, stream>>>(z1, W2, h2, N);
  k_gagg<32, float><<<(N + 7) / 8, 256, 0, stream>>>(row_start, adj, dinv, h2, b2, z2, N);

  k_decode<<<(EL + 7) / 8, 256, 0, stream>>>(eli, eli + EL, z2, (float*)d_out, EL);
}

// Round 5
// 592.905 us; speedup vs baseline: 2.4736x; 1.1656x over previous
//
#include <hip/hip_runtime.h>
#include <hip/hip_bf16.h>

typedef __hip_bfloat16 bf16;

__device__ __forceinline__ float ldval(float v) { return v; }
__device__ __forceinline__ float ldval(bf16 v) { return __bfloat162float(v); }

#define SCAN_BLK 2048   // 256 threads x 8 elements
#define BSHIFT 8        // 256 dest nodes per bucket
#define BNODES 256
#define CHUNK 4096      // edges per binpass block
#define SORT_CAP 12288  // bucket-sort LDS capacity (48 KB); mean bucket = 8192

// ---- degree count (self-loop added as +1 in k_dinv) ----
__global__ __launch_bounds__(256) void k_deg(const int* __restrict__ col, int E,
                                             unsigned* __restrict__ deg) {
  int e = blockIdx.x * 256 + threadIdx.x;
  if (e < E) atomicAdd(&deg[col[e]], 1u);
}

__global__ __launch_bounds__(256) void k_dinv(const unsigned* __restrict__ deg,
                                              float* __restrict__ dinv, int n) {
  int i = blockIdx.x * 256 + threadIdx.x;
  if (i < n) dinv[i] = rsqrtf((float)deg[i] + 1.0f);  // +1 = self-loop
}

// ---- scan phase 1: per-block (2048-chunk) sums ----
__global__ __launch_bounds__(256) void k_part(const unsigned* __restrict__ deg, int n,
                                              int* __restrict__ part) {
  __shared__ int sm[256];
  int t = threadIdx.x;
  int base = blockIdx.x * SCAN_BLK + t * 8;
  int s = 0;
#pragma unroll
  for (int i = 0; i < 8; i++) {
    int idx = base + i;
    if (idx < n) s += (int)deg[idx];
  }
  sm[t] = s;
  __syncthreads();
  for (int d = 128; d > 0; d >>= 1) {
    if (t < d) sm[t] += sm[t + d];
    __syncthreads();
  }
  if (t == 0) part[blockIdx.x] = sm[0];
}

// ---- scan phase 2: exclusive-scan the partials (tiny) ----
__global__ __launch_bounds__(64) void k_scanpart(int* __restrict__ part, int nb,
                                                 int* __restrict__ row_start, int n) {
  if (threadIdx.x == 0) {
    int off = 0;
    for (int b = 0; b < nb; b++) { int v = part[b]; part[b] = off; off += v; }
    row_start[n] = off;  // == E
  }
}

// ---- scan phase 3: row_start + cursor + per-bucket base cursors ----
__global__ __launch_bounds__(256) void k_rowstart(const unsigned* __restrict__ deg, int n,
                                                  const int* __restrict__ part,
                                                  int* __restrict__ row_start,
                                                  int* __restrict__ cursor,
                                                  int* __restrict__ bcur) {
  __shared__ int sm[256];
  int t = threadIdx.x;
  int base = blockIdx.x * SCAN_BLK + t * 8;
  int v[8];
  int s = 0;
#pragma unroll
  for (int i = 0; i < 8; i++) {
    int idx = base + i;
    v[i] = (idx < n) ? (int)deg[idx] : 0;
    s += v[i];
  }
  sm[t] = s;
  __syncthreads();
  for (int d = 1; d < 256; d <<= 1) {   // Hillis-Steele inclusive
    int x = (t >= d) ? sm[t - d] : 0;
    __syncthreads();
    sm[t] += x;
    __syncthreads();
  }
  int off = part[blockIdx.x] + ((t == 0) ? 0 : sm[t - 1]);
#pragma unroll
  for (int i = 0; i < 8; i++) {
    int idx = base + i;
    if (idx < n) {
      row_start[idx] = off;
      cursor[idx] = off;
      if ((idx & (BNODES - 1)) == 0) bcur[idx >> BSHIFT] = off;
      off += v[i];
    }
  }
}

// ---- bin pass: group edges by 256-node bucket, coalesced-run writes ----
// adjTmp entry: r | (c_low << 17)   (r < 2^17, c_low < 256)
__global__ __launch_bounds__(256) void k_binpass(const int* __restrict__ row,
                                                 const int* __restrict__ col, int E,
                                                 int nbuck,
                                                 int* __restrict__ bcur,
                                                 int* __restrict__ adjTmp) {
  __shared__ int hist[512];
  __shared__ int base[512];
  __shared__ int lcur[512];
  __shared__ int gbase[512];
  __shared__ int psum[256];
  __shared__ int stage[CHUNK];
  __shared__ unsigned short sbkt[CHUNK];
  __shared__ int s_total;
  int t = threadIdx.x;
  int e0 = blockIdx.x * CHUNK;

  hist[t] = 0; hist[t + 256] = 0;
  __syncthreads();

  int pk[16], bk[16];
#pragma unroll
  for (int i = 0; i < 16; i++) {
    int e = e0 + i * 256 + t;
    if (e < E) {
      int c = col[e];
      int r = row[e];
      bk[i] = c >> BSHIFT;
      pk[i] = r | ((c & (BNODES - 1)) << 17);
      atomicAdd(&hist[bk[i]], 1);
    } else bk[i] = -1;
  }
  __syncthreads();
  // exclusive scan of hist[0..511] (each thread owns a pair)
  int a0 = hist[2 * t], a1 = hist[2 * t + 1];
  psum[t] = a0 + a1;
  __syncthreads();
  for (int d = 1; d < 256; d <<= 1) {
    int v = (t >= d) ? psum[t - d] : 0;
    __syncthreads();
    psum[t] += v;
    __syncthreads();
  }
  int pref = (t == 0) ? 0 : psum[t - 1];
  base[2 * t] = pref;      lcur[2 * t] = pref;
  base[2 * t + 1] = pref + a0; lcur[2 * t + 1] = pref + a0;
  if (t == 255) s_total = psum[255];
  // reserve contiguous global runs (few hundred atomics per block)
  for (int b = t; b < nbuck; b += 256) {
    int h = hist[b];
    if (h > 0) gbase[b] = atomicAdd(&bcur[b], h);
  }
  __syncthreads();
#pragma unroll
  for (int i = 0; i < 16; i++) {
    if (bk[i] >= 0) {
      int pos = atomicAdd(&lcur[bk[i]], 1);
      stage[pos] = pk[i];
      sbkt[pos] = (unsigned short)bk[i];
    }
  }
  __syncthreads();
  int total = s_total;
  for (int i = t; i < total; i += 256) {
    int b = sbkt[i];
    adjTmp[gbase[b] + (i - base[b])] = stage[i];
  }
}

// ---- bucket sort: one block per bucket, LDS counting sort, coalesced out ----
__global__ __launch_bounds__(256) void k_bucketsort(const int* __restrict__ row_start,
                                                    const int* __restrict__ adjTmp,
                                                    int* __restrict__ cursor,
                                                    int* __restrict__ adj, int n) {
  __shared__ int cur[BNODES];
  __shared__ int stage[SORT_CAP];
  int b = blockIdx.x;
  int t = threadIdx.x;
  int node_base = b << BSHIFT;
  int nnode = min(BNODES, n - node_base);
  int seg_base = row_start[node_base];
  int seg_end = row_start[min(node_base + BNODES, n)];
  int cnt = seg_end - seg_base;
  if (cnt <= SORT_CAP) {
    if (t < nnode) cur[t] = row_start[node_base + t] - seg_base;
    __syncthreads();
    for (int i = t; i < cnt; i += 256) {
      int p = adjTmp[seg_base + i];
      int pos = atomicAdd(&cur[p >> 17], 1);
      stage[pos] = p & 0x1FFFF;
    }
    __syncthreads();
    for (int i = t; i < cnt; i += 256) adj[seg_base + i] = stage[i];
  } else {
    // fallback (statistically never; cursor[] pre-seeded with row_start)
    for (int i = t; i < cnt; i += 256) {
      int p = adjTmp[seg_base + i];
      int pos = atomicAdd(&cursor[node_base + (p >> 17)], 1);
      adj[pos] = p & 0x1FFFF;
    }
  }
}

// ---- g1[n,64] = dinv[r] * (x[n,128] @ W1[128,64]), bf16 out ----
__global__ __launch_bounds__(256) void k_gemm1(const float* __restrict__ x,
                                               const float* __restrict__ W,
                                               const float* __restrict__ dinv,
                                               bf16* __restrict__ h, int n) {
  __shared__ float Ws[128 * 64];   // 32 KB
  __shared__ float xs[4 * 128];    // 2 KB
  int tid = threadIdx.x;
  for (int i = tid; i < 128 * 64 / 4; i += 256)
    ((float4*)Ws)[i] = ((const float4*)W)[i];
  long r0 = (long)blockIdx.x * 4;
  if (r0 * 128 + 512 <= (long)n * 128) {
    const float4* xsrc = (const float4*)(x + r0 * 128);
    for (int i = tid; i < 128; i += 256) ((float4*)xs)[i] = xsrc[i];
  } else {
    for (int i = tid; i < 512; i += 256) {
      long idx = r0 * 128 + i;
      xs[i] = (idx < (long)n * 128) ? x[idx] : 0.f;
    }
  }
  __syncthreads();
  int c = tid & 63, rr = tid >> 6;
  int r = (int)r0 + rr;
  if (r >= n) return;
  const float* xr = &xs[rr * 128];
  float a0 = 0.f, a1 = 0.f, a2 = 0.f, a3 = 0.f;
#pragma unroll
  for (int k = 0; k < 128; k += 4) {
    a0 = fmaf(xr[k + 0], Ws[(k + 0) * 64 + c], a0);
    a1 = fmaf(xr[k + 1], Ws[(k + 1) * 64 + c], a1);
    a2 = fmaf(xr[k + 2], Ws[(k + 2) * 64 + c], a2);
    a3 = fmaf(xr[k + 3], Ws[(k + 3) * 64 + c], a3);
  }
  h[r * 64 + c] = __float2bfloat16(((a0 + a1) + (a2 + a3)) * dinv[r]);
}

// ---- CSR gather-aggregate: z[c] = dinv[c]*(g[c] + sum g[r]) + bias ----
template <int F, typename T>
__global__ __launch_bounds__(256) void k_gagg(const int* __restrict__ row_start,
                                              const int* __restrict__ adj,
                                              const float* __restrict__ dinv,
                                              const T* __restrict__ g,
                                              const float* __restrict__ bias,
                                              float* __restrict__ z, int n) {
  constexpr int PER = 256 / F;
  int lane = threadIdx.x & (F - 1);
  int c = blockIdx.x * PER + (threadIdx.x / F);
  if (c >= n) return;
  float acc = ldval(g[(long)c * F + lane]);   // self-loop
  int j = row_start[c];
  int end = row_start[c + 1];
  for (; j + 4 <= end; j += 4) {
    int r0 = adj[j], r1 = adj[j + 1], r2 = adj[j + 2], r3 = adj[j + 3];
    float v0 = ldval(g[(long)r0 * F + lane]);
    float v1 = ldval(g[(long)r1 * F + lane]);
    float v2 = ldval(g[(long)r2 * F + lane]);
    float v3 = ldval(g[(long)r3 * F + lane]);
    acc += v0; acc += v1; acc += v2; acc += v3;
  }
  for (; j < end; j++) acc += ldval(g[(long)adj[j] * F + lane]);
  z[(long)c * F + lane] = fmaf(dinv[c], acc, bias[lane]);
}

// ---- g2[n,32] = dinv[r] * (relu(z1[n,64]) @ W2[64,32]), fp32 ----
__global__ __launch_bounds__(256) void k_gemm2(const float* __restrict__ z1,
                                               const float* __restrict__ W,
                                               const float* __restrict__ dinv,
                                               float* __restrict__ h, int n) {
  __shared__ float Ws[64 * 32];   // 8 KB
  __shared__ float zs[8 * 64];    // 2 KB
  int tid = threadIdx.x;
  for (int i = tid; i < 64 * 32 / 4; i += 256)
    ((float4*)Ws)[i] = ((const float4*)W)[i];
  long r0 = (long)blockIdx.x * 8;
  for (int i = tid; i < 8 * 64; i += 256) {
    long idx = r0 * 64 + i;
    zs[i] = (idx < (long)n * 64) ? fmaxf(z1[idx], 0.f) : 0.f;  // relu folded
  }
  __syncthreads();
  int c = tid & 31, rr = tid >> 5;
  int r = (int)r0 + rr;
  if (r >= n) return;
  const float* zr = &zs[rr * 64];
  float a0 = 0.f, a1 = 0.f, a2 = 0.f, a3 = 0.f;
#pragma unroll
  for (int k = 0; k < 64; k += 4) {
    a0 = fmaf(zr[k + 0], Ws[(k + 0) * 32 + c], a0);
    a1 = fmaf(zr[k + 1], Ws[(k + 1) * 32 + c], a1);
    a2 = fmaf(zr[k + 2], Ws[(k + 2) * 32 + c], a2);
    a3 = fmaf(zr[k + 3], Ws[(k + 3) * 32 + c], a3);
  }
  h[r * 32 + c] = ((a0 + a1) + (a2 + a3)) * dinv[r];
}

// ---- link decode: half-wave per label edge, shuffle reduce, fp32 out ----
__global__ __launch_bounds__(256) void k_decode(const int* __restrict__ ea,
                                                const int* __restrict__ eb,
                                                const float* __restrict__ z2,
                                                float* __restrict__ out, int EL) {
  int lane = threadIdx.x & 31;
  int e = blockIdx.x * 8 + (threadIdx.x >> 5);
  if (e >= EL) return;
  int a = ea[e], b = eb[e];
  float p = z2[a * 32 + lane] * z2[b * 32 + lane];
  p += __shfl_down(p, 16);
  p += __shfl_down(p, 8);
  p += __shfl_down(p, 4);
  p += __shfl_down(p, 2);
  p += __shfl_down(p, 1);
  if (lane == 0) out[e] = p;
}

extern "C" void kernel_launch(void* const* d_in, const int* in_sizes, int n_in,
                              void* d_out, int out_size, void* d_ws, size_t ws_size,
                              hipStream_t stream) {
  const float* x   = (const float*)d_in[0];
  const float* W1  = (const float*)d_in[1];
  const float* b1  = (const float*)d_in[2];
  const float* W2  = (const float*)d_in[3];
  const float* b2  = (const float*)d_in[4];
  const int*   ei  = (const int*)d_in[5];   // [2,E]: row=ei[0..E), col=ei[E..2E)
  const int*   eli = (const int*)d_in[6];   // [2,EL]

  const int N  = in_sizes[0] / 128;  // 100000
  const int E  = in_sizes[5] / 2;    // 3200000
  const int EL = in_sizes[6] / 2;    // 200000
  const int* row = ei;
  const int* col = ei + E;
  const int NB    = (N + SCAN_BLK - 1) / SCAN_BLK;    // 49
  const int NBUCK = (N + BNODES - 1) / BNODES;        // 391
  const int NCHNK = (E + CHUNK - 1) / CHUNK;          // 782

  // workspace (~66 MB)
  char* ws = (char*)d_ws;
  size_t off = 0;
  auto take = [&](size_t bytes) { char* p = ws + off; off += (bytes + 255) & ~(size_t)255; return p; };
  unsigned* deg       = (unsigned*)take((size_t)N * 4);
  float*    dinv      = (float*)take((size_t)N * 4);
  int*      row_start = (int*)take((size_t)(N + 1) * 4);
  int*      cursor    = (int*)take((size_t)N * 4);
  int*      part      = (int*)take((size_t)NB * 4);
  int*      bcur      = (int*)take((size_t)NBUCK * 4);
  int*      adjTmp    = (int*)take((size_t)E * 4);
  int*      adj       = (int*)take((size_t)E * 4);
  char*     bufH      = take((size_t)N * 64 * 2);     // g1 bf16 / g2 f32 (12.8MB)
  float*    bufZ      = (float*)take((size_t)N * 64 * 4);
  (void)ws_size; (void)n_in; (void)out_size;

  bf16*  g1 = (bf16*)bufH;
  float* g2 = (float*)bufH;   // aliases g1 (g1 dead when g2 written)
  float* z1 = bufZ;
  float* z2 = bufZ;           // aliases z1 front (z1 dead when z2 written)

  hipMemsetAsync(deg, 0, (size_t)N * 4, stream);
  k_deg       <<<(E + 255) / 256, 256, 0, stream>>>(col, E, deg);
  k_dinv      <<<(N + 255) / 256, 256, 0, stream>>>(deg, dinv, N);
  k_part      <<<NB, 256, 0, stream>>>(deg, N, part);
  k_scanpart  <<<1, 64, 0, stream>>>(part, NB, row_start, N);
  k_rowstart  <<<NB, 256, 0, stream>>>(deg, N, part, row_start, cursor, bcur);
  k_binpass   <<<NCHNK, 256, 0, stream>>>(row, col, E, NBUCK, bcur, adjTmp);
  k_bucketsort<<<NBUCK, 256, 0, stream>>>(row_start, adjTmp, cursor, adj, N);

  k_gemm1<<<(N + 3) / 4, 256, 0, stream>>>(x, W1, dinv, g1, N);
  k_gagg<64, bf16><<<(N + 3) / 4, 256, 0, stream>>>(row_start, adj, dinv, g1, b1, z1, N);

  k_gemm2<<<(N + 7) / 8, 256, 0, stream>>>(z1, W2, dinv, g2, N);
  k_gagg<32, float><<<(N + 7) / 8, 256, 0, stream>>>(row_start, adj, dinv, g2, b2, z2, N);

  k_decode<<<(EL + 7) / 8, 256, 0, stream>>>(eli, eli + EL, z2, (float*)d_out, EL);
}

// Round 6
// 475.892 us; speedup vs baseline: 3.0818x; 1.2459x over previous
//
#include <hip/hip_runtime.h>
#include <hip/hip_bf16.h>

typedef __hip_bfloat16 bf16;

__device__ __forceinline__ float ldval(float v) { return v; }
__device__ __forceinline__ float ldval(bf16 v) { return __bfloat162float(v); }

#define BSHIFT 8        // 256 dest nodes per bucket
#define BNODES 256
#define CHUNK 4096      // edges per chunk
#define SORT_CAP 12288  // bucket-sort LDS capacity (48 KB); mean bucket = 8192, ~45 sigma

// ---- phase 1: per-chunk bucket histogram (LDS atomics only) ----
__global__ __launch_bounds__(256) void k_hist(const int* __restrict__ col, int E,
                                              int nbuck, int* __restrict__ chist) {
  __shared__ int hist[512];
  int t = threadIdx.x;
  hist[t] = 0; hist[t + 256] = 0;
  __syncthreads();
  int e0 = blockIdx.x * CHUNK;
#pragma unroll
  for (int i = 0; i < 16; i++) {
    int e = e0 + i * 256 + t;
    if (e < E) atomicAdd(&hist[col[e] >> BSHIFT], 1);
  }
  __syncthreads();
  int* out = chist + (size_t)blockIdx.x * nbuck;
  for (int b = t; b < nbuck; b += 256) out[b] = hist[b];  // coalesced
}

// ---- phase 2: per-bucket exclusive scan over chunks (in place) ----
__global__ __launch_bounds__(256) void k_scanbuck(int* __restrict__ chist, int nchnk,
                                                  int nbuck, int* __restrict__ btot) {
  __shared__ int sm[256];
  int b = blockIdx.x, t = threadIdx.x;
  int per = (nchnk + 255) / 256;
  int lo = t * per, hi = min(lo + per, nchnk);
  int s = 0;
  for (int i = lo; i < hi; i++) s += chist[(size_t)i * nbuck + b];
  sm[t] = s;
  __syncthreads();
  for (int d = 1; d < 256; d <<= 1) {   // Hillis-Steele inclusive
    int x = (t >= d) ? sm[t - d] : 0;
    __syncthreads();
    sm[t] += x;
    __syncthreads();
  }
  int off = (t == 0) ? 0 : sm[t - 1];
  for (int i = lo; i < hi; i++) {
    int c = chist[(size_t)i * nbuck + b];
    chist[(size_t)i * nbuck + b] = off;
    off += c;
  }
  if (t == 255) btot[b] = sm[255];
}

// ---- phase 3: scan bucket totals (tiny serial) ----
__global__ __launch_bounds__(64) void k_scanbase(const int* __restrict__ btot, int nbuck,
                                                 int* __restrict__ bbase,
                                                 int* __restrict__ row_start, int n) {
  if (threadIdx.x == 0) {
    int off = 0;
    for (int b = 0; b < nbuck; b++) { bbase[b] = off; off += btot[b]; }
    bbase[nbuck] = off;
    row_start[n] = off;  // == E
  }
}

// ---- phase 4: grouped scatter into bucket-sorted adjTmp, NO global atomics ----
// adjTmp entry: r | (c_low << 17)   (r < 2^17, c_low < 256)
__global__ __launch_bounds__(256) void k_binpass(const int* __restrict__ row,
                                                 const int* __restrict__ col, int E,
                                                 int nbuck,
                                                 const int* __restrict__ bbase,
                                                 const int* __restrict__ chist,
                                                 int* __restrict__ adjTmp) {
  __shared__ int hist[512];
  __shared__ int base[512];
  __shared__ int lcur[512];
  __shared__ int gbase[512];
  __shared__ int psum[256];
  __shared__ int stage[CHUNK];
  __shared__ unsigned short sbkt[CHUNK];
  __shared__ int s_total;
  int t = threadIdx.x;
  int e0 = blockIdx.x * CHUNK;

  hist[t] = 0; hist[t + 256] = 0;
  __syncthreads();

  int pk[16], bk[16];
#pragma unroll
  for (int i = 0; i < 16; i++) {
    int e = e0 + i * 256 + t;
    if (e < E) {
      int c = col[e];
      int r = row[e];
      bk[i] = c >> BSHIFT;
      pk[i] = r | ((c & (BNODES - 1)) << 17);
      atomicAdd(&hist[bk[i]], 1);
    } else bk[i] = -1;
  }
  __syncthreads();
  // exclusive scan of hist[0..511] (each thread owns a pair)
  int a0 = hist[2 * t], a1 = hist[2 * t + 1];
  psum[t] = a0 + a1;
  __syncthreads();
  for (int d = 1; d < 256; d <<= 1) {
    int v = (t >= d) ? psum[t - d] : 0;
    __syncthreads();
    psum[t] += v;
    __syncthreads();
  }
  int pref = (t == 0) ? 0 : psum[t - 1];
  base[2 * t] = pref;          lcur[2 * t] = pref;
  base[2 * t + 1] = pref + a0; lcur[2 * t + 1] = pref + a0;
  if (t == 255) s_total = psum[255];
  // global run bases: precomputed, no atomics
  const int* coff = chist + (size_t)blockIdx.x * nbuck;
  for (int b = t; b < nbuck; b += 256) gbase[b] = bbase[b] + coff[b];
  __syncthreads();
#pragma unroll
  for (int i = 0; i < 16; i++) {
    if (bk[i] >= 0) {
      int pos = atomicAdd(&lcur[bk[i]], 1);
      stage[pos] = pk[i];
      sbkt[pos] = (unsigned short)bk[i];
    }
  }
  __syncthreads();
  int total = s_total;
  for (int i = t; i < total; i += 256) {
    int b = sbkt[i];
    adjTmp[gbase[b] + (i - base[b])] = stage[i];
  }
}

// ---- phase 5: per-bucket sort; emits deg->dinv, row_start, sorted adj ----
__global__ __launch_bounds__(256) void k_bucketsort(const int* __restrict__ bbase,
                                                    const int* __restrict__ adjTmp,
                                                    int* __restrict__ adj,
                                                    int* __restrict__ row_start,
                                                    float* __restrict__ dinv, int n) {
  __shared__ int cnt[BNODES];
  __shared__ int sc[BNODES];
  __shared__ int cur[BNODES];
  __shared__ int stage[SORT_CAP];
  int b = blockIdx.x, t = threadIdx.x;
  int node_base = b << BSHIFT;
  int nnode = min(BNODES, n - node_base);
  int seg_base = bbase[b];
  int cntE = bbase[b + 1] - seg_base;
  cnt[t] = 0;
  __syncthreads();
  for (int i = t; i < cntE; i += 256) atomicAdd(&cnt[adjTmp[seg_base + i] >> 17], 1);
  __syncthreads();
  int myc = cnt[t];
  sc[t] = myc;
  __syncthreads();
  for (int d = 1; d < 256; d <<= 1) {   // Hillis-Steele inclusive
    int x = (t >= d) ? sc[t - d] : 0;
    __syncthreads();
    sc[t] += x;
    __syncthreads();
  }
  int excl = (t == 0) ? 0 : sc[t - 1];
  cur[t] = excl;
  if (t < nnode) {
    row_start[node_base + t] = seg_base + excl;
    dinv[node_base + t] = rsqrtf((float)myc + 1.0f);  // +1 = self-loop
  }
  __syncthreads();
  if (cntE <= SORT_CAP) {
    for (int i = t; i < cntE; i += 256) {
      int p = adjTmp[seg_base + i];
      int pos = atomicAdd(&cur[p >> 17], 1);
      stage[pos] = p & 0x1FFFF;
    }
    __syncthreads();
    for (int i = t; i < cntE; i += 256) adj[seg_base + i] = stage[i];  // coalesced
  } else {
    // fallback (statistically never)
    for (int i = t; i < cntE; i += 256) {
      int p = adjTmp[seg_base + i];
      int pos = atomicAdd(&cur[p >> 17], 1);
      adj[seg_base + pos] = p & 0x1FFFF;
    }
  }
}

// ---- g1[n,64] = dinv[r] * (x[n,128] @ W1[128,64]), bf16 out ----
__global__ __launch_bounds__(256) void k_gemm1(const float* __restrict__ x,
                                               const float* __restrict__ W,
                                               const float* __restrict__ dinv,
                                               bf16* __restrict__ h, int n) {
  __shared__ float Ws[128 * 64];   // 32 KB
  __shared__ float xs[4 * 128];    // 2 KB
  int tid = threadIdx.x;
  for (int i = tid; i < 128 * 64 / 4; i += 256)
    ((float4*)Ws)[i] = ((const float4*)W)[i];
  long r0 = (long)blockIdx.x * 4;
  if (r0 * 128 + 512 <= (long)n * 128) {
    const float4* xsrc = (const float4*)(x + r0 * 128);
    for (int i = tid; i < 128; i += 256) ((float4*)xs)[i] = xsrc[i];
  } else {
    for (int i = tid; i < 512; i += 256) {
      long idx = r0 * 128 + i;
      xs[i] = (idx < (long)n * 128) ? x[idx] : 0.f;
    }
  }
  __syncthreads();
  int c = tid & 63, rr = tid >> 6;
  int r = (int)r0 + rr;
  if (r >= n) return;
  const float* xr = &xs[rr * 128];
  float a0 = 0.f, a1 = 0.f, a2 = 0.f, a3 = 0.f;
#pragma unroll
  for (int k = 0; k < 128; k += 4) {
    a0 = fmaf(xr[k + 0], Ws[(k + 0) * 64 + c], a0);
    a1 = fmaf(xr[k + 1], Ws[(k + 1) * 64 + c], a1);
    a2 = fmaf(xr[k + 2], Ws[(k + 2) * 64 + c], a2);
    a3 = fmaf(xr[k + 3], Ws[(k + 3) * 64 + c], a3);
  }
  h[r * 64 + c] = __float2bfloat16(((a0 + a1) + (a2 + a3)) * dinv[r]);
}

// ---- CSR gather-aggregate: z[c] = dinv[c]*(g[c] + sum g[r]) + bias ----
template <int F, typename T>
__global__ __launch_bounds__(256) void k_gagg(const int* __restrict__ row_start,
                                              const int* __restrict__ adj,
                                              const float* __restrict__ dinv,
                                              const T* __restrict__ g,
                                              const float* __restrict__ bias,
                                              float* __restrict__ z, int n) {
  constexpr int PER = 256 / F;
  int lane = threadIdx.x & (F - 1);
  int c = blockIdx.x * PER + (threadIdx.x / F);
  if (c >= n) return;
  float acc = ldval(g[(long)c * F + lane]);   // self-loop
  int j = row_start[c];
  int end = row_start[c + 1];
  for (; j + 4 <= end; j += 4) {
    int r0 = adj[j], r1 = adj[j + 1], r2 = adj[j + 2], r3 = adj[j + 3];
    float v0 = ldval(g[(long)r0 * F + lane]);
    float v1 = ldval(g[(long)r1 * F + lane]);
    float v2 = ldval(g[(long)r2 * F + lane]);
    float v3 = ldval(g[(long)r3 * F + lane]);
    acc += v0; acc += v1; acc += v2; acc += v3;
  }
  for (; j < end; j++) acc += ldval(g[(long)adj[j] * F + lane]);
  z[(long)c * F + lane] = fmaf(dinv[c], acc, bias[lane]);
}

// ---- g2[n,32] = dinv[r] * (relu(z1[n,64]) @ W2[64,32]), fp32 ----
__global__ __launch_bounds__(256) void k_gemm2(const float* __restrict__ z1,
                                               const float* __restrict__ W,
                                               const float* __restrict__ dinv,
                                               float* __restrict__ h, int n) {
  __shared__ float Ws[64 * 32];   // 8 KB
  __shared__ float zs[8 * 64];    // 2 KB
  int tid = threadIdx.x;
  for (int i = tid; i < 64 * 32 / 4; i += 256)
    ((float4*)Ws)[i] = ((const float4*)W)[i];
  long r0 = (long)blockIdx.x * 8;
  for (int i = tid; i < 8 * 64; i += 256) {
    long idx = r0 * 64 + i;
    zs[i] = (idx < (long)n * 64) ? fmaxf(z1[idx], 0.f) : 0.f;  // relu folded
  }
  __syncthreads();
  int c = tid & 31, rr = tid >> 5;
  int r = (int)r0 + rr;
  if (r >= n) return;
  const float* zr = &zs[rr * 64];
  float a0 = 0.f, a1 = 0.f, a2 = 0.f, a3 = 0.f;
#pragma unroll
  for (int k = 0; k < 64; k += 4) {
    a0 = fmaf(zr[k + 0], Ws[(k + 0) * 32 + c], a0);
    a1 = fmaf(zr[k + 1], Ws[(k + 1) * 32 + c], a1);
    a2 = fmaf(zr[k + 2], Ws[(k + 2) * 32 + c], a2);
    a3 = fmaf(zr[k + 3], Ws[(k + 3) * 32 + c], a3);
  }
  h[r * 32 + c] = ((a0 + a1) + (a2 + a3)) * dinv[r];
}

// ---- link decode: half-wave per label edge, shuffle reduce, fp32 out ----
__global__ __launch_bounds__(256) void k_decode(const int* __restrict__ ea,
                                                const int* __restrict__ eb,
                                                const float* __restrict__ z2,
                                                float* __restrict__ out, int EL) {
  int lane = threadIdx.x & 31;
  int e = blockIdx.x * 8 + (threadIdx.x >> 5);
  if (e >= EL) return;
  int a = ea[e], b = eb[e];
  float p = z2[a * 32 + lane] * z2[b * 32 + lane];
  p += __shfl_down(p, 16);
  p += __shfl_down(p, 8);
  p += __shfl_down(p, 4);
  p += __shfl_down(p, 2);
  p += __shfl_down(p, 1);
  if (lane == 0) out[e] = p;
}

extern "C" void kernel_launch(void* const* d_in, const int* in_sizes, int n_in,
                              void* d_out, int out_size, void* d_ws, size_t ws_size,
                              hipStream_t stream) {
  const float* x   = (const float*)d_in[0];
  const float* W1  = (const float*)d_in[1];
  const float* b1  = (const float*)d_in[2];
  const float* W2  = (const float*)d_in[3];
  const float* b2  = (const float*)d_in[4];
  const int*   ei  = (const int*)d_in[5];   // [2,E]: row=ei[0..E), col=ei[E..2E)
  const int*   eli = (const int*)d_in[6];   // [2,EL]

  const int N  = in_sizes[0] / 128;  // 100000
  const int E  = in_sizes[5] / 2;    // 3200000
  const int EL = in_sizes[6] / 2;    // 200000
  const int* row = ei;
  const int* col = ei + E;
  const int NBUCK = (N + BNODES - 1) / BNODES;   // 391
  const int NCHNK = (E + CHUNK - 1) / CHUNK;     // 782

  // workspace (~66 MB)
  char* ws = (char*)d_ws;
  size_t off = 0;
  auto take = [&](size_t bytes) { char* p = ws + off; off += (bytes + 255) & ~(size_t)255; return p; };
  float* dinv      = (float*)take((size_t)N * 4);
  int*   row_start = (int*)take((size_t)(N + 1) * 4);
  int*   btot      = (int*)take((size_t)NBUCK * 4);
  int*   bbase     = (int*)take((size_t)(NBUCK + 1) * 4);
  int*   chist     = (int*)take((size_t)NCHNK * NBUCK * 4);   // 1.22 MB
  int*   adjTmp    = (int*)take((size_t)E * 4);               // 12.8 MB
  int*   adj       = (int*)take((size_t)E * 4);               // 12.8 MB
  char*  bufH      = take((size_t)N * 64 * 2);                // g1 bf16 / g2 f32
  float* bufZ      = (float*)take((size_t)N * 64 * 4);        // z1 / z2
  (void)ws_size; (void)n_in; (void)out_size;

  bf16*  g1 = (bf16*)bufH;
  float* g2 = (float*)bufH;   // aliases g1 (g1 dead when g2 written)
  float* z1 = bufZ;
  float* z2 = bufZ;           // aliases z1 front (z1 dead when z2 written)

  k_hist      <<<NCHNK, 256, 0, stream>>>(col, E, NBUCK, chist);
  k_scanbuck  <<<NBUCK, 256, 0, stream>>>(chist, NCHNK, NBUCK, btot);
  k_scanbase  <<<1, 64, 0, stream>>>(btot, NBUCK, bbase, row_start, N);
  k_binpass   <<<NCHNK, 256, 0, stream>>>(row, col, E, NBUCK, bbase, chist, adjTmp);
  k_bucketsort<<<NBUCK, 256, 0, stream>>>(bbase, adjTmp, adj, row_start, dinv, N);

  k_gemm1<<<(N + 3) / 4, 256, 0, stream>>>(x, W1, dinv, g1, N);
  k_gagg<64, bf16><<<(N + 3) / 4, 256, 0, stream>>>(row_start, adj, dinv, g1, b1, z1, N);

  k_gemm2<<<(N + 7) / 8, 256, 0, stream>>>(z1, W2, dinv, g2, N);
  k_gagg<32, float><<<(N + 7) / 8, 256, 0, stream>>>(row_start, adj, dinv, g2, b2, z2, N);

  k_decode<<<(EL + 7) / 8, 256, 0, stream>>>(eli, eli + EL, z2, (float*)d_out, EL);
}

// Round 7
// 392.737 us; speedup vs baseline: 3.7344x; 1.2117x over previous
//
#include <hip/hip_runtime.h>
#include <hip/hip_bf16.h>

typedef __hip_bfloat16 bf16;
typedef short s8v __attribute__((ext_vector_type(8)));   // 8 bf16 in 4 VGPRs
typedef float f4v __attribute__((ext_vector_type(4)));   // MFMA 16x16 C/D frag

__device__ __forceinline__ float ldval(float v) { return v; }
__device__ __forceinline__ float ldval(bf16 v) { return __bfloat162float(v); }
__device__ __forceinline__ short f2b(float f) {
  bf16 h = __float2bfloat16(f);
  return *reinterpret_cast<short*>(&h);
}

#define BSHIFT 8        // 256 dest nodes per bucket
#define BNODES 256
#define CHUNK 4096      // edges per chunk
#define SORT_CAP 12288  // bucket-sort LDS capacity (48 KB); mean bucket = 8192

// ---- phase 1: per-chunk bucket histogram (LDS atomics only) ----
__global__ __launch_bounds__(256) void k_hist(const int* __restrict__ col, int E,
                                              int nbuck, int* __restrict__ chist) {
  __shared__ int hist[512];
  int t = threadIdx.x;
  hist[t] = 0; hist[t + 256] = 0;
  __syncthreads();
  int e0 = blockIdx.x * CHUNK;
#pragma unroll
  for (int i = 0; i < 16; i++) {
    int e = e0 + i * 256 + t;
    if (e < E) atomicAdd(&hist[col[e] >> BSHIFT], 1);
  }
  __syncthreads();
  int* out = chist + (size_t)blockIdx.x * nbuck;
  for (int b = t; b < nbuck; b += 256) out[b] = hist[b];  // coalesced
}

// ---- phase 2: per-bucket exclusive scan over chunks (in place) ----
__global__ __launch_bounds__(256) void k_scanbuck(int* __restrict__ chist, int nchnk,
                                                  int nbuck, int* __restrict__ btot) {
  __shared__ int sm[256];
  int b = blockIdx.x, t = threadIdx.x;
  int per = (nchnk + 255) / 256;
  int lo = t * per, hi = min(lo + per, nchnk);
  int s = 0;
  for (int i = lo; i < hi; i++) s += chist[(size_t)i * nbuck + b];
  sm[t] = s;
  __syncthreads();
  for (int d = 1; d < 256; d <<= 1) {
    int x = (t >= d) ? sm[t - d] : 0;
    __syncthreads();
    sm[t] += x;
    __syncthreads();
  }
  int off = (t == 0) ? 0 : sm[t - 1];
  for (int i = lo; i < hi; i++) {
    int c = chist[(size_t)i * nbuck + b];
    chist[(size_t)i * nbuck + b] = off;
    off += c;
  }
  if (t == 255) btot[b] = sm[255];
}

// ---- phase 3: scan bucket totals (tiny serial) ----
__global__ __launch_bounds__(64) void k_scanbase(const int* __restrict__ btot, int nbuck,
                                                 int* __restrict__ bbase,
                                                 int* __restrict__ row_start, int n) {
  if (threadIdx.x == 0) {
    int off = 0;
    for (int b = 0; b < nbuck; b++) { bbase[b] = off; off += btot[b]; }
    bbase[nbuck] = off;
    row_start[n] = off;  // == E
  }
}

// ---- phase 4: grouped scatter into bucket-sorted adjTmp, NO global atomics ----
// adjTmp entry: r | (c_low << 17)
__global__ __launch_bounds__(256) void k_binpass(const int* __restrict__ row,
                                                 const int* __restrict__ col, int E,
                                                 int nbuck,
                                                 const int* __restrict__ bbase,
                                                 const int* __restrict__ chist,
                                                 int* __restrict__ adjTmp) {
  __shared__ int hist[512];
  __shared__ int base[512];
  __shared__ int lcur[512];
  __shared__ int gbase[512];
  __shared__ int psum[256];
  __shared__ int stage[CHUNK];
  __shared__ unsigned short sbkt[CHUNK];
  __shared__ int s_total;
  int t = threadIdx.x;
  int e0 = blockIdx.x * CHUNK;

  hist[t] = 0; hist[t + 256] = 0;
  __syncthreads();

  int pk[16], bk[16];
#pragma unroll
  for (int i = 0; i < 16; i++) {
    int e = e0 + i * 256 + t;
    if (e < E) {
      int c = col[e];
      int r = row[e];
      bk[i] = c >> BSHIFT;
      pk[i] = r | ((c & (BNODES - 1)) << 17);
      atomicAdd(&hist[bk[i]], 1);
    } else bk[i] = -1;
  }
  __syncthreads();
  int a0 = hist[2 * t], a1 = hist[2 * t + 1];
  psum[t] = a0 + a1;
  __syncthreads();
  for (int d = 1; d < 256; d <<= 1) {
    int v = (t >= d) ? psum[t - d] : 0;
    __syncthreads();
    psum[t] += v;
    __syncthreads();
  }
  int pref = (t == 0) ? 0 : psum[t - 1];
  base[2 * t] = pref;          lcur[2 * t] = pref;
  base[2 * t + 1] = pref + a0; lcur[2 * t + 1] = pref + a0;
  if (t == 255) s_total = psum[255];
  const int* coff = chist + (size_t)blockIdx.x * nbuck;
  for (int b = t; b < nbuck; b += 256) gbase[b] = bbase[b] + coff[b];
  __syncthreads();
#pragma unroll
  for (int i = 0; i < 16; i++) {
    if (bk[i] >= 0) {
      int pos = atomicAdd(&lcur[bk[i]], 1);
      stage[pos] = pk[i];
      sbkt[pos] = (unsigned short)bk[i];
    }
  }
  __syncthreads();
  int total = s_total;
  for (int i = t; i < total; i += 256) {
    int b = sbkt[i];
    adjTmp[gbase[b] + (i - base[b])] = stage[i];
  }
}

// ---- phase 5: per-bucket sort; emits deg->dinv, row_start, sorted adj ----
__global__ __launch_bounds__(256) void k_bucketsort(const int* __restrict__ bbase,
                                                    const int* __restrict__ adjTmp,
                                                    int* __restrict__ adj,
                                                    int* __restrict__ row_start,
                                                    float* __restrict__ dinv, int n) {
  __shared__ int cnt[BNODES];
  __shared__ int sc[BNODES];
  __shared__ int cur[BNODES];
  __shared__ int stage[SORT_CAP];
  int b = blockIdx.x, t = threadIdx.x;
  int node_base = b << BSHIFT;
  int nnode = min(BNODES, n - node_base);
  int seg_base = bbase[b];
  int cntE = bbase[b + 1] - seg_base;
  cnt[t] = 0;
  __syncthreads();
  for (int i = t; i < cntE; i += 256) atomicAdd(&cnt[adjTmp[seg_base + i] >> 17], 1);
  __syncthreads();
  int myc = cnt[t];
  sc[t] = myc;
  __syncthreads();
  for (int d = 1; d < 256; d <<= 1) {
    int x = (t >= d) ? sc[t - d] : 0;
    __syncthreads();
    sc[t] += x;
    __syncthreads();
  }
  int excl = (t == 0) ? 0 : sc[t - 1];
  cur[t] = excl;
  if (t < nnode) {
    row_start[node_base + t] = seg_base + excl;
    dinv[node_base + t] = rsqrtf((float)myc + 1.0f);  // +1 = self-loop
  }
  __syncthreads();
  if (cntE <= SORT_CAP) {
    for (int i = t; i < cntE; i += 256) {
      int p = adjTmp[seg_base + i];
      int pos = atomicAdd(&cur[p >> 17], 1);
      stage[pos] = p & 0x1FFFF;
    }
    __syncthreads();
    for (int i = t; i < cntE; i += 256) adj[seg_base + i] = stage[i];
  } else {
    for (int i = t; i < cntE; i += 256) {
      int p = adjTmp[seg_base + i];
      int pos = atomicAdd(&cur[p >> 17], 1);
      adj[seg_base + pos] = p & 0x1FFFF;
    }
  }
}

// ---- weight prep: Wt1[64][128] = W1^T bf16, Wt2[32][64] = W2^T bf16 ----
__global__ __launch_bounds__(256) void k_prepW(const float* __restrict__ W1,
                                               const float* __restrict__ W2,
                                               short* __restrict__ Wt1,
                                               short* __restrict__ Wt2) {
  int t = blockIdx.x * 256 + threadIdx.x;
  if (t < 128 * 64) { int k = t >> 6, c = t & 63; Wt1[c * 128 + k] = f2b(W1[t]); }
  if (t < 64 * 32)  { int k = t >> 5, c = t & 31; Wt2[c * 64 + k] = f2b(W2[t]); }
}

// ---- MFMA gemm1: g1[n,64] = dinv[r]*(x[n,128] @ W1[128,64]), bf16 out ----
// block = 4 waves x 16 rows = 64 rows; mfma_f32_16x16x32_bf16
__global__ __launch_bounds__(256) void k_gemm1(const float* __restrict__ x,
                                               const short* __restrict__ Wt,  // [64][128] bf16
                                               const float* __restrict__ dinv,
                                               bf16* __restrict__ g1, int n) {
  int wave = threadIdx.x >> 6;
  int lane = threadIdx.x & 63;
  int m = lane & 15;       // A row within tile / B col within tile / C col
  int quad = lane >> 4;    // k-group (A/B), row-group (C)
  int r = blockIdx.x * 64 + wave * 16 + m;

  s8v afr[4];
  if (r < n) {
    const float* ap = x + (size_t)r * 128 + quad * 8;
#pragma unroll
    for (int kc = 0; kc < 4; kc++) {
      float4 u = *(const float4*)(ap + kc * 32);
      float4 v = *(const float4*)(ap + kc * 32 + 4);
      s8v a;
      a[0] = f2b(u.x); a[1] = f2b(u.y); a[2] = f2b(u.z); a[3] = f2b(u.w);
      a[4] = f2b(v.x); a[5] = f2b(v.y); a[6] = f2b(v.z); a[7] = f2b(v.w);
      afr[kc] = a;
    }
  } else {
#pragma unroll
    for (int kc = 0; kc < 4; kc++) afr[kc] = (s8v)(short)0;
  }

  const short* wp = Wt + (size_t)m * 128 + quad * 8;
  s8v bfr[4][4];  // [nt][kc]
#pragma unroll
  for (int nt = 0; nt < 4; nt++)
#pragma unroll
    for (int kc = 0; kc < 4; kc++)
      bfr[nt][kc] = *(const s8v*)(wp + nt * 16 * 128 + kc * 32);

  f4v acc[4] = {f4v{0,0,0,0}, f4v{0,0,0,0}, f4v{0,0,0,0}, f4v{0,0,0,0}};
#pragma unroll
  for (int kc = 0; kc < 4; kc++)
#pragma unroll
    for (int nt = 0; nt < 4; nt++)
      acc[nt] = __builtin_amdgcn_mfma_f32_16x16x32_bf16(afr[kc], bfr[nt][kc], acc[nt], 0, 0, 0);

  int rbase = blockIdx.x * 64 + wave * 16 + quad * 4;  // C row = quad*4+reg
#pragma unroll
  for (int reg = 0; reg < 4; reg++) {
    int rr = rbase + reg;
    if (rr < n) {
      float dv = dinv[rr];
#pragma unroll
      for (int nt = 0; nt < 4; nt++)
        g1[(size_t)rr * 64 + nt * 16 + m] = __float2bfloat16(acc[nt][reg] * dv);
    }
  }
}

// ---- MFMA gemm2: g2[n,32] = dinv[r]*(z1b[n,64] @ W2[64,32]), f32 out ----
__global__ __launch_bounds__(256) void k_gemm2(const bf16* __restrict__ z1b,
                                               const short* __restrict__ Wt,  // [32][64] bf16
                                               const float* __restrict__ dinv,
                                               float* __restrict__ g2, int n) {
  int wave = threadIdx.x >> 6;
  int lane = threadIdx.x & 63;
  int m = lane & 15;
  int quad = lane >> 4;
  int r = blockIdx.x * 64 + wave * 16 + m;

  s8v afr[2];
  if (r < n) {
    const short* ap = (const short*)z1b + (size_t)r * 64 + quad * 8;
#pragma unroll
    for (int kc = 0; kc < 2; kc++) afr[kc] = *(const s8v*)(ap + kc * 32);
  } else {
#pragma unroll
    for (int kc = 0; kc < 2; kc++) afr[kc] = (s8v)(short)0;
  }

  const short* wp = Wt + (size_t)m * 64 + quad * 8;
  s8v bfr[2][2];  // [nt][kc]
#pragma unroll
  for (int nt = 0; nt < 2; nt++)
#pragma unroll
    for (int kc = 0; kc < 2; kc++)
      bfr[nt][kc] = *(const s8v*)(wp + nt * 16 * 64 + kc * 32);

  f4v acc[2] = {f4v{0,0,0,0}, f4v{0,0,0,0}};
#pragma unroll
  for (int kc = 0; kc < 2; kc++)
#pragma unroll
    for (int nt = 0; nt < 2; nt++)
      acc[nt] = __builtin_amdgcn_mfma_f32_16x16x32_bf16(afr[kc], bfr[nt][kc], acc[nt], 0, 0, 0);

  int rbase = blockIdx.x * 64 + wave * 16 + quad * 4;
#pragma unroll
  for (int reg = 0; reg < 4; reg++) {
    int rr = rbase + reg;
    if (rr < n) {
      float dv = dinv[rr];
#pragma unroll
      for (int nt = 0; nt < 2; nt++)
        g2[(size_t)rr * 32 + nt * 16 + m] = acc[nt][reg] * dv;
    }
  }
}

// ---- CSR gather-aggregate: z[c] = dinv[c]*(g[c] + sum g[r]) + bias ----
// TOUT=bf16 + RELU=true -> writes relu'd bf16 (feeds MFMA gemm2)
template <int F, typename TIN, typename TOUT, bool RELU>
__global__ __launch_bounds__(256) void k_gagg(const int* __restrict__ row_start,
                                              const int* __restrict__ adj,
                                              const float* __restrict__ dinv,
                                              const TIN* __restrict__ g,
                                              const float* __restrict__ bias,
                                              TOUT* __restrict__ z, int n) {
  constexpr int PER = 256 / F;
  int lane = threadIdx.x & (F - 1);
  int c = blockIdx.x * PER + (threadIdx.x / F);
  if (c >= n) return;
  float acc = ldval(g[(long)c * F + lane]);   // self-loop
  int j = row_start[c];
  int end = row_start[c + 1];
  for (; j + 4 <= end; j += 4) {
    int r0 = adj[j], r1 = adj[j + 1], r2 = adj[j + 2], r3 = adj[j + 3];
    float v0 = ldval(g[(long)r0 * F + lane]);
    float v1 = ldval(g[(long)r1 * F + lane]);
    float v2 = ldval(g[(long)r2 * F + lane]);
    float v3 = ldval(g[(long)r3 * F + lane]);
    acc += v0; acc += v1; acc += v2; acc += v3;
  }
  for (; j < end; j++) acc += ldval(g[(long)adj[j] * F + lane]);
  float v = fmaf(dinv[c], acc, bias[lane]);
  if (RELU) v = fmaxf(v, 0.f);
  if constexpr (sizeof(TOUT) == 2)
    z[(long)c * F + lane] = __float2bfloat16(v);
  else
    z[(long)c * F + lane] = v;
}

// ---- link decode: half-wave per label edge, shuffle reduce, fp32 out ----
__global__ __launch_bounds__(256) void k_decode(const int* __restrict__ ea,
                                                const int* __restrict__ eb,
                                                const float* __restrict__ z2,
                                                float* __restrict__ out, int EL) {
  int lane = threadIdx.x & 31;
  int e = blockIdx.x * 8 + (threadIdx.x >> 5);
  if (e >= EL) return;
  int a = ea[e], b = eb[e];
  float p = z2[a * 32 + lane] * z2[b * 32 + lane];
  p += __shfl_down(p, 16);
  p += __shfl_down(p, 8);
  p += __shfl_down(p, 4);
  p += __shfl_down(p, 2);
  p += __shfl_down(p, 1);
  if (lane == 0) out[e] = p;
}

extern "C" void kernel_launch(void* const* d_in, const int* in_sizes, int n_in,
                              void* d_out, int out_size, void* d_ws, size_t ws_size,
                              hipStream_t stream) {
  const float* x   = (const float*)d_in[0];
  const float* W1  = (const float*)d_in[1];
  const float* b1  = (const float*)d_in[2];
  const float* W2  = (const float*)d_in[3];
  const float* b2  = (const float*)d_in[4];
  const int*   ei  = (const int*)d_in[5];   // [2,E]: row=ei[0..E), col=ei[E..2E)
  const int*   eli = (const int*)d_in[6];   // [2,EL]

  const int N  = in_sizes[0] / 128;  // 100000
  const int E  = in_sizes[5] / 2;    // 3200000
  const int EL = in_sizes[6] / 2;    // 200000
  const int* row = ei;
  const int* col = ei + E;
  const int NBUCK = (N + BNODES - 1) / BNODES;   // 391
  const int NCHNK = (E + CHUNK - 1) / CHUNK;     // 782

  // workspace (~66 MB)
  char* ws = (char*)d_ws;
  size_t off = 0;
  auto take = [&](size_t bytes) { char* p = ws + off; off += (bytes + 255) & ~(size_t)255; return p; };
  float* dinv      = (float*)take((size_t)N * 4);
  int*   row_start = (int*)take((size_t)(N + 1) * 4);
  int*   btot      = (int*)take((size_t)NBUCK * 4);
  int*   bbase     = (int*)take((size_t)(NBUCK + 1) * 4);
  short* Wt1       = (short*)take((size_t)64 * 128 * 2);
  short* Wt2       = (short*)take((size_t)32 * 64 * 2);
  int*   chist     = (int*)take((size_t)NCHNK * NBUCK * 4);   // 1.22 MB
  int*   adjTmp    = (int*)take((size_t)E * 4);               // 12.8 MB
  int*   adj       = (int*)take((size_t)E * 4);               // 12.8 MB
  char*  bufH      = take((size_t)N * 64 * 2);                // g1 bf16 / g2 f32
  bf16*  z1b       = (bf16*)take((size_t)N * 64 * 2);         // relu'd, bf16
  float* z2        = (float*)take((size_t)N * 32 * 4);
  (void)ws_size; (void)n_in; (void)out_size;

  bf16*  g1 = (bf16*)bufH;
  float* g2 = (float*)bufH;   // aliases g1 (g1 dead when g2 written)

  k_prepW     <<<32, 256, 0, stream>>>(W1, W2, Wt1, Wt2);
  k_hist      <<<NCHNK, 256, 0, stream>>>(col, E, NBUCK, chist);
  k_scanbuck  <<<NBUCK, 256, 0, stream>>>(chist, NCHNK, NBUCK, btot);
  k_scanbase  <<<1, 64, 0, stream>>>(btot, NBUCK, bbase, row_start, N);
  k_binpass   <<<NCHNK, 256, 0, stream>>>(row, col, E, NBUCK, bbase, chist, adjTmp);
  k_bucketsort<<<NBUCK, 256, 0, stream>>>(bbase, adjTmp, adj, row_start, dinv, N);

  k_gemm1<<<(N + 63) / 64, 256, 0, stream>>>(x, Wt1, dinv, g1, N);
  k_gagg<64, bf16, bf16, true><<<(N + 3) / 4, 256, 0, stream>>>(row_start, adj, dinv, g1, b1, z1b, N);

  k_gemm2<<<(N + 63) / 64, 256, 0, stream>>>(z1b, Wt2, dinv, g2, N);
  k_gagg<32, float, float, false><<<(N + 7) / 8, 256, 0, stream>>>(row_start, adj, dinv, g2, b2, z2, N);

  k_decode<<<(EL + 7) / 8, 256, 0, stream>>>(eli, eli + EL, z2, (float*)d_out, EL);
}

// Round 8
// 342.336 us; speedup vs baseline: 4.2842x; 1.1472x over previous
//
#include <hip/hip_runtime.h>
#include <hip/hip_bf16.h>

typedef __hip_bfloat16 bf16;
typedef short s8v __attribute__((ext_vector_type(8)));   // 8 bf16 in 4 VGPRs
typedef float f4v __attribute__((ext_vector_type(4)));   // MFMA 16x16 C/D frag

__device__ __forceinline__ short f2b(float f) {
  bf16 h = __float2bfloat16(f);
  return *reinterpret_cast<short*>(&h);
}
// accumulate 4 bf16 (packed in int2, memory order) into float4
__device__ __forceinline__ void bf4_acc(int2 pk, float4& a) {
  a.x += __int_as_float(pk.x << 16);
  a.y += __int_as_float(pk.x & 0xFFFF0000);
  a.z += __int_as_float(pk.y << 16);
  a.w += __int_as_float(pk.y & 0xFFFF0000);
}

#define BSHIFT 8        // 256 dest nodes per bucket
#define BNODES 256
#define CHUNK 4096      // edges per chunk
#define SORT_CAP 12288  // bucket-sort LDS capacity (48 KB); mean bucket = 8192

// ---- phase 1: per-chunk bucket histogram (LDS atomics only) ----
__global__ __launch_bounds__(256) void k_hist(const int* __restrict__ col, int E,
                                              int nbuck, int* __restrict__ chist) {
  __shared__ int hist[512];
  int t = threadIdx.x;
  hist[t] = 0; hist[t + 256] = 0;
  __syncthreads();
  int e0 = blockIdx.x * CHUNK;
#pragma unroll
  for (int i = 0; i < 16; i++) {
    int e = e0 + i * 256 + t;
    if (e < E) atomicAdd(&hist[col[e] >> BSHIFT], 1);
  }
  __syncthreads();
  int* out = chist + (size_t)blockIdx.x * nbuck;
  for (int b = t; b < nbuck; b += 256) out[b] = hist[b];  // coalesced
}

// ---- phase 2: per-bucket exclusive scan over chunks (in place) ----
__global__ __launch_bounds__(256) void k_scanbuck(int* __restrict__ chist, int nchnk,
                                                  int nbuck, int* __restrict__ btot) {
  __shared__ int sm[256];
  int b = blockIdx.x, t = threadIdx.x;
  int per = (nchnk + 255) / 256;
  int lo = t * per, hi = min(lo + per, nchnk);
  int s = 0;
  for (int i = lo; i < hi; i++) s += chist[(size_t)i * nbuck + b];
  sm[t] = s;
  __syncthreads();
  for (int d = 1; d < 256; d <<= 1) {
    int x = (t >= d) ? sm[t - d] : 0;
    __syncthreads();
    sm[t] += x;
    __syncthreads();
  }
  int off = (t == 0) ? 0 : sm[t - 1];
  for (int i = lo; i < hi; i++) {
    int c = chist[(size_t)i * nbuck + b];
    chist[(size_t)i * nbuck + b] = off;
    off += c;
  }
  if (t == 255) btot[b] = sm[255];
}

// ---- phase 3: scan bucket totals (tiny serial) ----
__global__ __launch_bounds__(64) void k_scanbase(const int* __restrict__ btot, int nbuck,
                                                 int* __restrict__ bbase,
                                                 int* __restrict__ row_start, int n) {
  if (threadIdx.x == 0) {
    int off = 0;
    for (int b = 0; b < nbuck; b++) { bbase[b] = off; off += btot[b]; }
    bbase[nbuck] = off;
    row_start[n] = off;  // == E
  }
}

// ---- phase 4: grouped scatter into bucket-sorted adjTmp, NO global atomics ----
// adjTmp entry: r | (c_low << 17)
__global__ __launch_bounds__(256) void k_binpass(const int* __restrict__ row,
                                                 const int* __restrict__ col, int E,
                                                 int nbuck,
                                                 const int* __restrict__ bbase,
                                                 const int* __restrict__ chist,
                                                 int* __restrict__ adjTmp) {
  __shared__ int hist[512];
  __shared__ int base[512];
  __shared__ int lcur[512];
  __shared__ int gbase[512];
  __shared__ int psum[256];
  __shared__ int stage[CHUNK];
  __shared__ unsigned short sbkt[CHUNK];
  __shared__ int s_total;
  int t = threadIdx.x;
  int e0 = blockIdx.x * CHUNK;

  hist[t] = 0; hist[t + 256] = 0;
  __syncthreads();

  int pk[16], bk[16];
#pragma unroll
  for (int i = 0; i < 16; i++) {
    int e = e0 + i * 256 + t;
    if (e < E) {
      int c = col[e];
      int r = row[e];
      bk[i] = c >> BSHIFT;
      pk[i] = r | ((c & (BNODES - 1)) << 17);
      atomicAdd(&hist[bk[i]], 1);
    } else bk[i] = -1;
  }
  __syncthreads();
  int a0 = hist[2 * t], a1 = hist[2 * t + 1];
  psum[t] = a0 + a1;
  __syncthreads();
  for (int d = 1; d < 256; d <<= 1) {
    int v = (t >= d) ? psum[t - d] : 0;
    __syncthreads();
    psum[t] += v;
    __syncthreads();
  }
  int pref = (t == 0) ? 0 : psum[t - 1];
  base[2 * t] = pref;          lcur[2 * t] = pref;
  base[2 * t + 1] = pref + a0; lcur[2 * t + 1] = pref + a0;
  if (t == 255) s_total = psum[255];
  const int* coff = chist + (size_t)blockIdx.x * nbuck;
  for (int b = t; b < nbuck; b += 256) gbase[b] = bbase[b] + coff[b];
  __syncthreads();
#pragma unroll
  for (int i = 0; i < 16; i++) {
    if (bk[i] >= 0) {
      int pos = atomicAdd(&lcur[bk[i]], 1);
      stage[pos] = pk[i];
      sbkt[pos] = (unsigned short)bk[i];
    }
  }
  __syncthreads();
  int total = s_total;
  for (int i = t; i < total; i += 256) {
    int b = sbkt[i];
    adjTmp[gbase[b] + (i - base[b])] = stage[i];
  }
}

// ---- phase 5: per-bucket sort; emits deg->dinv, row_start, sorted adj ----
__global__ __launch_bounds__(256) void k_bucketsort(const int* __restrict__ bbase,
                                                    const int* __restrict__ adjTmp,
                                                    int* __restrict__ adj,
                                                    int* __restrict__ row_start,
                                                    float* __restrict__ dinv, int n) {
  __shared__ int cnt[BNODES];
  __shared__ int sc[BNODES];
  __shared__ int cur[BNODES];
  __shared__ int stage[SORT_CAP];
  int b = blockIdx.x, t = threadIdx.x;
  int node_base = b << BSHIFT;
  int nnode = min(BNODES, n - node_base);
  int seg_base = bbase[b];
  int cntE = bbase[b + 1] - seg_base;
  cnt[t] = 0;
  __syncthreads();
  for (int i = t; i < cntE; i += 256) atomicAdd(&cnt[adjTmp[seg_base + i] >> 17], 1);
  __syncthreads();
  int myc = cnt[t];
  sc[t] = myc;
  __syncthreads();
  for (int d = 1; d < 256; d <<= 1) {
    int x = (t >= d) ? sc[t - d] : 0;
    __syncthreads();
    sc[t] += x;
    __syncthreads();
  }
  int excl = (t == 0) ? 0 : sc[t - 1];
  cur[t] = excl;
  if (t < nnode) {
    row_start[node_base + t] = seg_base + excl;
    dinv[node_base + t] = rsqrtf((float)myc + 1.0f);  // +1 = self-loop
  }
  __syncthreads();
  if (cntE <= SORT_CAP) {
    for (int i = t; i < cntE; i += 256) {
      int p = adjTmp[seg_base + i];
      int pos = atomicAdd(&cur[p >> 17], 1);
      stage[pos] = p & 0x1FFFF;
    }
    __syncthreads();
    for (int i = t; i < cntE; i += 256) adj[seg_base + i] = stage[i];
  } else {
    for (int i = t; i < cntE; i += 256) {
      int p = adjTmp[seg_base + i];
      int pos = atomicAdd(&cur[p >> 17], 1);
      adj[seg_base + pos] = p & 0x1FFFF;
    }
  }
}

// ---- weight prep: Wt1[64][128] = W1^T bf16, Wt2[32][64] = W2^T bf16 ----
__global__ __launch_bounds__(256) void k_prepW(const float* __restrict__ W1,
                                               const float* __restrict__ W2,
                                               short* __restrict__ Wt1,
                                               short* __restrict__ Wt2) {
  int t = blockIdx.x * 256 + threadIdx.x;
  if (t < 128 * 64) { int k = t >> 6, c = t & 63; Wt1[c * 128 + k] = f2b(W1[t]); }
  if (t < 64 * 32)  { int k = t >> 5, c = t & 31; Wt2[c * 64 + k] = f2b(W2[t]); }
}

// ---- MFMA gemm1: g1[n,64] = dinv[r]*(x[n,128] @ W1[128,64]), bf16 out ----
__global__ __launch_bounds__(256) void k_gemm1(const float* __restrict__ x,
                                               const short* __restrict__ Wt,  // [64][128] bf16
                                               const float* __restrict__ dinv,
                                               bf16* __restrict__ g1, int n) {
  int wave = threadIdx.x >> 6;
  int lane = threadIdx.x & 63;
  int m = lane & 15;
  int quad = lane >> 4;
  int r = blockIdx.x * 64 + wave * 16 + m;

  s8v afr[4];
  if (r < n) {
    const float* ap = x + (size_t)r * 128 + quad * 8;
#pragma unroll
    for (int kc = 0; kc < 4; kc++) {
      float4 u = *(const float4*)(ap + kc * 32);
      float4 v = *(const float4*)(ap + kc * 32 + 4);
      s8v a;
      a[0] = f2b(u.x); a[1] = f2b(u.y); a[2] = f2b(u.z); a[3] = f2b(u.w);
      a[4] = f2b(v.x); a[5] = f2b(v.y); a[6] = f2b(v.z); a[7] = f2b(v.w);
      afr[kc] = a;
    }
  } else {
#pragma unroll
    for (int kc = 0; kc < 4; kc++) afr[kc] = (s8v)(short)0;
  }

  const short* wp = Wt + (size_t)m * 128 + quad * 8;
  s8v bfr[4][4];
#pragma unroll
  for (int nt = 0; nt < 4; nt++)
#pragma unroll
    for (int kc = 0; kc < 4; kc++)
      bfr[nt][kc] = *(const s8v*)(wp + nt * 16 * 128 + kc * 32);

  f4v acc[4] = {f4v{0,0,0,0}, f4v{0,0,0,0}, f4v{0,0,0,0}, f4v{0,0,0,0}};
#pragma unroll
  for (int kc = 0; kc < 4; kc++)
#pragma unroll
    for (int nt = 0; nt < 4; nt++)
      acc[nt] = __builtin_amdgcn_mfma_f32_16x16x32_bf16(afr[kc], bfr[nt][kc], acc[nt], 0, 0, 0);

  int rbase = blockIdx.x * 64 + wave * 16 + quad * 4;
#pragma unroll
  for (int reg = 0; reg < 4; reg++) {
    int rr = rbase + reg;
    if (rr < n) {
      float dv = dinv[rr];
#pragma unroll
      for (int nt = 0; nt < 4; nt++)
        g1[(size_t)rr * 64 + nt * 16 + m] = __float2bfloat16(acc[nt][reg] * dv);
    }
  }
}

// ---- MFMA gemm2: g2[n,32] = dinv[r]*(z1b[n,64] @ W2[64,32]), bf16 out ----
__global__ __launch_bounds__(256) void k_gemm2(const bf16* __restrict__ z1b,
                                               const short* __restrict__ Wt,  // [32][64] bf16
                                               const float* __restrict__ dinv,
                                               short* __restrict__ g2, int n) {
  int wave = threadIdx.x >> 6;
  int lane = threadIdx.x & 63;
  int m = lane & 15;
  int quad = lane >> 4;
  int r = blockIdx.x * 64 + wave * 16 + m;

  s8v afr[2];
  if (r < n) {
    const short* ap = (const short*)z1b + (size_t)r * 64 + quad * 8;
#pragma unroll
    for (int kc = 0; kc < 2; kc++) afr[kc] = *(const s8v*)(ap + kc * 32);
  } else {
#pragma unroll
    for (int kc = 0; kc < 2; kc++) afr[kc] = (s8v)(short)0;
  }

  const short* wp = Wt + (size_t)m * 64 + quad * 8;
  s8v bfr[2][2];
#pragma unroll
  for (int nt = 0; nt < 2; nt++)
#pragma unroll
    for (int kc = 0; kc < 2; kc++)
      bfr[nt][kc] = *(const s8v*)(wp + nt * 16 * 64 + kc * 32);

  f4v acc[2] = {f4v{0,0,0,0}, f4v{0,0,0,0}};
#pragma unroll
  for (int kc = 0; kc < 2; kc++)
#pragma unroll
    for (int nt = 0; nt < 2; nt++)
      acc[nt] = __builtin_amdgcn_mfma_f32_16x16x32_bf16(afr[kc], bfr[nt][kc], acc[nt], 0, 0, 0);

  int rbase = blockIdx.x * 64 + wave * 16 + quad * 4;
#pragma unroll
  for (int reg = 0; reg < 4; reg++) {
    int rr = rbase + reg;
    if (rr < n) {
      float dv = dinv[rr];
#pragma unroll
      for (int nt = 0; nt < 2; nt++)
        g2[(size_t)rr * 32 + nt * 16 + m] = f2b(acc[nt][reg] * dv);
    }
  }
}

// ---- layer-1 aggregate: 1 wave/dest, 16 lanes x 8B per edge (4 edges/inst) ----
// z1b[c,:] = relu(dinv[c]*(g1[c,:] + sum g1[r,:]) + b1)   (bf16 out)
__global__ __launch_bounds__(256) void k_gagg1(const int* __restrict__ row_start,
                                               const int* __restrict__ adj,
                                               const float* __restrict__ dinv,
                                               const short* __restrict__ g,   // g1 bf16 [n][64]
                                               const float* __restrict__ bias,
                                               short* __restrict__ z, int n) {
  int wave = threadIdx.x >> 6;
  int lane = threadIdx.x & 63;
  int grp = lane >> 4;     // 0..3: edge slot
  int fl = lane & 15;      // feature lane: feats fl*4..fl*4+3
  int c = blockIdx.x * 4 + wave;
  if (c >= n) return;
  int start = row_start[c], end = row_start[c + 1];
  float4 acc = {0.f, 0.f, 0.f, 0.f};
  int j = start;
  for (; j + 16 <= end; j += 16) {       // 16 edges in flight per iter
#pragma unroll
    for (int u = 0; u < 4; u++) {
      int r = adj[j + u * 4 + grp];
      int2 pk = *(const int2*)(g + r * 64 + fl * 4);
      bf4_acc(pk, acc);
    }
  }
  for (; j < end; j += 4) {
    int e = j + grp;
    if (e < end) {
      int r = adj[e];
      int2 pk = *(const int2*)(g + r * 64 + fl * 4);
      bf4_acc(pk, acc);
    }
  }
  // reduce the 4 edge slots (lanes differing in bits 4-5)
  acc.x += __shfl_xor(acc.x, 16); acc.y += __shfl_xor(acc.y, 16);
  acc.z += __shfl_xor(acc.z, 16); acc.w += __shfl_xor(acc.w, 16);
  acc.x += __shfl_xor(acc.x, 32); acc.y += __shfl_xor(acc.y, 32);
  acc.z += __shfl_xor(acc.z, 32); acc.w += __shfl_xor(acc.w, 32);
  if (grp == 0) {
    int2 pk = *(const int2*)(g + c * 64 + fl * 4);   // self-loop
    bf4_acc(pk, acc);
    float d = dinv[c];
    float4 bs = *(const float4*)(bias + fl * 4);
    float v0 = fmaxf(fmaf(d, acc.x, bs.x), 0.f);
    float v1 = fmaxf(fmaf(d, acc.y, bs.y), 0.f);
    float v2 = fmaxf(fmaf(d, acc.z, bs.z), 0.f);
    float v3 = fmaxf(fmaf(d, acc.w, bs.w), 0.f);
    int2 out;
    out.x = (int)(unsigned short)f2b(v0) | ((int)f2b(v1) << 16);
    out.y = (int)(unsigned short)f2b(v2) | ((int)f2b(v3) << 16);
    *(int2*)(z + c * 64 + fl * 4) = out;
  }
}

// ---- layer-2 aggregate: 1 wave/dest, 8 lanes x 8B per edge (8 edges/inst) ----
// z2[c,:] = dinv[c]*(g2[c,:] + sum g2[r,:]) + b2   (f32 out)
__global__ __launch_bounds__(256) void k_gagg2(const int* __restrict__ row_start,
                                               const int* __restrict__ adj,
                                               const float* __restrict__ dinv,
                                               const short* __restrict__ g,   // g2 bf16 [n][32]
                                               const float* __restrict__ bias,
                                               float* __restrict__ z, int n) {
  int wave = threadIdx.x >> 6;
  int lane = threadIdx.x & 63;
  int grp = lane >> 3;     // 0..7: edge slot
  int fl = lane & 7;       // feats fl*4..fl*4+3
  int c = blockIdx.x * 4 + wave;
  if (c >= n) return;
  int start = row_start[c], end = row_start[c + 1];
  float4 acc = {0.f, 0.f, 0.f, 0.f};
  int j = start;
  for (; j + 32 <= end; j += 32) {       // 32 edges in flight per iter
#pragma unroll
    for (int u = 0; u < 4; u++) {
      int r = adj[j + u * 8 + grp];
      int2 pk = *(const int2*)(g + r * 32 + fl * 4);
      bf4_acc(pk, acc);
    }
  }
  for (; j < end; j += 8) {
    int e = j + grp;
    if (e < end) {
      int r = adj[e];
      int2 pk = *(const int2*)(g + r * 32 + fl * 4);
      bf4_acc(pk, acc);
    }
  }
  acc.x += __shfl_xor(acc.x, 8);  acc.y += __shfl_xor(acc.y, 8);
  acc.z += __shfl_xor(acc.z, 8);  acc.w += __shfl_xor(acc.w, 8);
  acc.x += __shfl_xor(acc.x, 16); acc.y += __shfl_xor(acc.y, 16);
  acc.z += __shfl_xor(acc.z, 16); acc.w += __shfl_xor(acc.w, 16);
  acc.x += __shfl_xor(acc.x, 32); acc.y += __shfl_xor(acc.y, 32);
  acc.z += __shfl_xor(acc.z, 32); acc.w += __shfl_xor(acc.w, 32);
  if (grp == 0) {
    int2 pk = *(const int2*)(g + c * 32 + fl * 4);   // self-loop
    bf4_acc(pk, acc);
    float d = dinv[c];
    float4 bs = *(const float4*)(bias + fl * 4);
    float4 out;
    out.x = fmaf(d, acc.x, bs.x);
    out.y = fmaf(d, acc.y, bs.y);
    out.z = fmaf(d, acc.z, bs.z);
    out.w = fmaf(d, acc.w, bs.w);
    *(float4*)(z + c * 32 + fl * 4) = out;
  }
}

// ---- link decode: half-wave per label edge, shuffle reduce, fp32 out ----
__global__ __launch_bounds__(256) void k_decode(const int* __restrict__ ea,
                                                const int* __restrict__ eb,
                                                const float* __restrict__ z2,
                                                float* __restrict__ out, int EL) {
  int lane = threadIdx.x & 31;
  int e = blockIdx.x * 8 + (threadIdx.x >> 5);
  if (e >= EL) return;
  int a = ea[e], b = eb[e];
  float p = z2[a * 32 + lane] * z2[b * 32 + lane];
  p += __shfl_down(p, 16);
  p += __shfl_down(p, 8);
  p += __shfl_down(p, 4);
  p += __shfl_down(p, 2);
  p += __shfl_down(p, 1);
  if (lane == 0) out[e] = p;
}

extern "C" void kernel_launch(void* const* d_in, const int* in_sizes, int n_in,
                              void* d_out, int out_size, void* d_ws, size_t ws_size,
                              hipStream_t stream) {
  const float* x   = (const float*)d_in[0];
  const float* W1  = (const float*)d_in[1];
  const float* b1  = (const float*)d_in[2];
  const float* W2  = (const float*)d_in[3];
  const float* b2  = (const float*)d_in[4];
  const int*   ei  = (const int*)d_in[5];   // [2,E]: row=ei[0..E), col=ei[E..2E)
  const int*   eli = (const int*)d_in[6];   // [2,EL]

  const int N  = in_sizes[0] / 128;  // 100000
  const int E  = in_sizes[5] / 2;    // 3200000
  const int EL = in_sizes[6] / 2;    // 200000
  const int* row = ei;
  const int* col = ei + E;
  const int NBUCK = (N + BNODES - 1) / BNODES;   // 391
  const int NCHNK = (E + CHUNK - 1) / CHUNK;     // 782

  // workspace (~60 MB)
  char* ws = (char*)d_ws;
  size_t off = 0;
  auto take = [&](size_t bytes) { char* p = ws + off; off += (bytes + 255) & ~(size_t)255; return p; };
  float* dinv      = (float*)take((size_t)N * 4);
  int*   row_start = (int*)take((size_t)(N + 1) * 4);
  int*   btot      = (int*)take((size_t)NBUCK * 4);
  int*   bbase     = (int*)take((size_t)(NBUCK + 1) * 4);
  short* Wt1       = (short*)take((size_t)64 * 128 * 2);
  short* Wt2       = (short*)take((size_t)32 * 64 * 2);
  int*   chist     = (int*)take((size_t)NCHNK * NBUCK * 4);   // 1.22 MB
  int*   adjTmp    = (int*)take((size_t)E * 4);               // 12.8 MB
  int*   adj       = (int*)take((size_t)E * 4);               // 12.8 MB
  char*  bufH      = take((size_t)N * 64 * 2);                // g1 bf16 / g2 bf16
  short* z1b       = (short*)take((size_t)N * 64 * 2);        // relu'd, bf16
  float* z2        = (float*)take((size_t)N * 32 * 4);
  (void)ws_size; (void)n_in; (void)out_size;

  bf16*  g1 = (bf16*)bufH;
  short* g2 = (short*)bufH;   // aliases g1 (g1 dead when g2 written)

  k_prepW     <<<32, 256, 0, stream>>>(W1, W2, Wt1, Wt2);
  k_hist      <<<NCHNK, 256, 0, stream>>>(col, E, NBUCK, chist);
  k_scanbuck  <<<NBUCK, 256, 0, stream>>>(chist, NCHNK, NBUCK, btot);
  k_scanbase  <<<1, 64, 0, stream>>>(btot, NBUCK, bbase, row_start, N);
  k_binpass   <<<NCHNK, 256, 0, stream>>>(row, col, E, NBUCK, bbase, chist, adjTmp);
  k_bucketsort<<<NBUCK, 256, 0, stream>>>(bbase, adjTmp, adj, row_start, dinv, N);

  k_gemm1<<<(N + 63) / 64, 256, 0, stream>>>(x, Wt1, dinv, g1, N);
  k_gagg1<<<(N + 3) / 4, 256, 0, stream>>>(row_start, adj, dinv, (const short*)g1, b1, z1b, N);

  k_gemm2<<<(N + 63) / 64, 256, 0, stream>>>((const bf16*)z1b, Wt2, dinv, g2, N);
  k_gagg2<<<(N + 3) / 4, 256, 0, stream>>>(row_start, adj, dinv, g2, b2, z2, N);

  k_decode<<<(EL + 7) / 8, 256, 0, stream>>>(eli, eli + EL, z2, (float*)d_out, EL);
}

// Round 9
// 323.024 us; speedup vs baseline: 4.5403x; 1.0598x over previous
//
#include <hip/hip_runtime.h>
#include <hip/hip_bf16.h>

typedef __hip_bfloat16 bf16;
typedef short s8v __attribute__((ext_vector_type(8)));   // 8 bf16 in 4 VGPRs
typedef float f4v __attribute__((ext_vector_type(4)));   // MFMA 16x16 C/D frag

__device__ __forceinline__ short f2b(float f) {
  bf16 h = __float2bfloat16(f);
  return *reinterpret_cast<short*>(&h);
}
// accumulate 4 bf16 (packed in 2 dwords, memory order) into float4
__device__ __forceinline__ void bf4_acc(int lo, int hi, float4& a) {
  a.x += __int_as_float(lo << 16);
  a.y += __int_as_float(lo & 0xFFFF0000);
  a.z += __int_as_float(hi << 16);
  a.w += __int_as_float(hi & 0xFFFF0000);
}

#define BSHIFT 8        // 256 dest nodes per bucket
#define BNODES 256
#define CHUNK 4096      // edges per chunk
#define SORT_CAP 12288  // bucket-sort LDS capacity (48 KB); mean bucket = 8192

// ---- phase 1: per-chunk bucket histogram (LDS atomics only) ----
__global__ __launch_bounds__(256) void k_hist(const int* __restrict__ col, int E,
                                              int nbuck, int* __restrict__ chist) {
  __shared__ int hist[512];
  int t = threadIdx.x;
  hist[t] = 0; hist[t + 256] = 0;
  __syncthreads();
  int e0 = blockIdx.x * CHUNK;
#pragma unroll
  for (int i = 0; i < 16; i++) {
    int e = e0 + i * 256 + t;
    if (e < E) atomicAdd(&hist[col[e] >> BSHIFT], 1);
  }
  __syncthreads();
  int* out = chist + (size_t)blockIdx.x * nbuck;
  for (int b = t; b < nbuck; b += 256) out[b] = hist[b];  // coalesced
}

// ---- phase 2: per-bucket exclusive scan over chunks (in place) ----
__global__ __launch_bounds__(256) void k_scanbuck(int* __restrict__ chist, int nchnk,
                                                  int nbuck, int* __restrict__ btot) {
  __shared__ int sm[256];
  int b = blockIdx.x, t = threadIdx.x;
  int per = (nchnk + 255) / 256;
  int lo = t * per, hi = min(lo + per, nchnk);
  int s = 0;
  for (int i = lo; i < hi; i++) s += chist[(size_t)i * nbuck + b];
  sm[t] = s;
  __syncthreads();
  for (int d = 1; d < 256; d <<= 1) {
    int x = (t >= d) ? sm[t - d] : 0;
    __syncthreads();
    sm[t] += x;
    __syncthreads();
  }
  int off = (t == 0) ? 0 : sm[t - 1];
  for (int i = lo; i < hi; i++) {
    int c = chist[(size_t)i * nbuck + b];
    chist[(size_t)i * nbuck + b] = off;
    off += c;
  }
  if (t == 255) btot[b] = sm[255];
}

// ---- phase 3: scan bucket totals (tiny serial) ----
__global__ __launch_bounds__(64) void k_scanbase(const int* __restrict__ btot, int nbuck,
                                                 int* __restrict__ bbase,
                                                 int* __restrict__ row_start, int n) {
  if (threadIdx.x == 0) {
    int off = 0;
    for (int b = 0; b < nbuck; b++) { bbase[b] = off; off += btot[b]; }
    bbase[nbuck] = off;
    row_start[n] = off;  // == E
  }
}

// ---- phase 4: grouped scatter into bucket-sorted adjTmp, NO global atomics ----
// adjTmp entry: r | (c_low << 17)
__global__ __launch_bounds__(256) void k_binpass(const int* __restrict__ row,
                                                 const int* __restrict__ col, int E,
                                                 int nbuck,
                                                 const int* __restrict__ bbase,
                                                 const int* __restrict__ chist,
                                                 int* __restrict__ adjTmp) {
  __shared__ int hist[512];
  __shared__ int base[512];
  __shared__ int lcur[512];
  __shared__ int gbase[512];
  __shared__ int psum[256];
  __shared__ int stage[CHUNK];
  __shared__ unsigned short sbkt[CHUNK];
  __shared__ int s_total;
  int t = threadIdx.x;
  int e0 = blockIdx.x * CHUNK;

  hist[t] = 0; hist[t + 256] = 0;
  __syncthreads();

  int pk[16], bk[16];
#pragma unroll
  for (int i = 0; i < 16; i++) {
    int e = e0 + i * 256 + t;
    if (e < E) {
      int c = col[e];
      int r = row[e];
      bk[i] = c >> BSHIFT;
      pk[i] = r | ((c & (BNODES - 1)) << 17);
      atomicAdd(&hist[bk[i]], 1);
    } else bk[i] = -1;
  }
  __syncthreads();
  int a0 = hist[2 * t], a1 = hist[2 * t + 1];
  psum[t] = a0 + a1;
  __syncthreads();
  for (int d = 1; d < 256; d <<= 1) {
    int v = (t >= d) ? psum[t - d] : 0;
    __syncthreads();
    psum[t] += v;
    __syncthreads();
  }
  int pref = (t == 0) ? 0 : psum[t - 1];
  base[2 * t] = pref;          lcur[2 * t] = pref;
  base[2 * t + 1] = pref + a0; lcur[2 * t + 1] = pref + a0;
  if (t == 255) s_total = psum[255];
  const int* coff = chist + (size_t)blockIdx.x * nbuck;
  for (int b = t; b < nbuck; b += 256) gbase[b] = bbase[b] + coff[b];
  __syncthreads();
#pragma unroll
  for (int i = 0; i < 16; i++) {
    if (bk[i] >= 0) {
      int pos = atomicAdd(&lcur[bk[i]], 1);
      stage[pos] = pk[i];
      sbkt[pos] = (unsigned short)bk[i];
    }
  }
  __syncthreads();
  int total = s_total;
  for (int i = t; i < total; i += 256) {
    int b = sbkt[i];
    adjTmp[gbase[b] + (i - base[b])] = stage[i];
  }
}

// ---- phase 5: per-bucket sort; emits deg->dinv, row_start, sorted adj ----
__global__ __launch_bounds__(256) void k_bucketsort(const int* __restrict__ bbase,
                                                    const int* __restrict__ adjTmp,
                                                    int* __restrict__ adj,
                                                    int* __restrict__ row_start,
                                                    float* __restrict__ dinv, int n) {
  __shared__ int cnt[BNODES];
  __shared__ int sc[BNODES];
  __shared__ int cur[BNODES];
  __shared__ int stage[SORT_CAP];
  int b = blockIdx.x, t = threadIdx.x;
  int node_base = b << BSHIFT;
  int nnode = min(BNODES, n - node_base);
  int seg_base = bbase[b];
  int cntE = bbase[b + 1] - seg_base;
  cnt[t] = 0;
  __syncthreads();
  for (int i = t; i < cntE; i += 256) atomicAdd(&cnt[adjTmp[seg_base + i] >> 17], 1);
  __syncthreads();
  int myc = cnt[t];
  sc[t] = myc;
  __syncthreads();
  for (int d = 1; d < 256; d <<= 1) {
    int x = (t >= d) ? sc[t - d] : 0;
    __syncthreads();
    sc[t] += x;
    __syncthreads();
  }
  int excl = (t == 0) ? 0 : sc[t - 1];
  cur[t] = excl;
  if (t < nnode) {
    row_start[node_base + t] = seg_base + excl;
    dinv[node_base + t] = rsqrtf((float)myc + 1.0f);  // +1 = self-loop
  }
  __syncthreads();
  if (cntE <= SORT_CAP) {
    for (int i = t; i < cntE; i += 256) {
      int p = adjTmp[seg_base + i];
      int pos = atomicAdd(&cur[p >> 17], 1);
      stage[pos] = p & 0x1FFFF;
    }
    __syncthreads();
    for (int i = t; i < cntE; i += 256) adj[seg_base + i] = stage[i];
  } else {
    for (int i = t; i < cntE; i += 256) {
      int p = adjTmp[seg_base + i];
      int pos = atomicAdd(&cur[p >> 17], 1);
      adj[seg_base + pos] = p & 0x1FFFF;
    }
  }
}

// ---- weight prep: Wt1[64][128] = W1^T bf16, Wt2[32][64] = W2^T bf16 ----
__global__ __launch_bounds__(256) void k_prepW(const float* __restrict__ W1,
                                               const float* __restrict__ W2,
                                               short* __restrict__ Wt1,
                                               short* __restrict__ Wt2) {
  int t = blockIdx.x * 256 + threadIdx.x;
  if (t < 128 * 64) { int k = t >> 6, c = t & 63; Wt1[c * 128 + k] = f2b(W1[t]); }
  if (t < 64 * 32)  { int k = t >> 5, c = t & 31; Wt2[c * 64 + k] = f2b(W2[t]); }
}

// ---- MFMA gemm1: g1[n,64] = dinv[r]*(x[n,128] @ W1[128,64]), bf16 out ----
__global__ __launch_bounds__(256) void k_gemm1(const float* __restrict__ x,
                                               const short* __restrict__ Wt,  // [64][128] bf16
                                               const float* __restrict__ dinv,
                                               bf16* __restrict__ g1, int n) {
  int wave = threadIdx.x >> 6;
  int lane = threadIdx.x & 63;
  int m = lane & 15;
  int quad = lane >> 4;
  int r = blockIdx.x * 64 + wave * 16 + m;

  s8v afr[4];
  if (r < n) {
    const float* ap = x + (size_t)r * 128 + quad * 8;
#pragma unroll
    for (int kc = 0; kc < 4; kc++) {
      float4 u = *(const float4*)(ap + kc * 32);
      float4 v = *(const float4*)(ap + kc * 32 + 4);
      s8v a;
      a[0] = f2b(u.x); a[1] = f2b(u.y); a[2] = f2b(u.z); a[3] = f2b(u.w);
      a[4] = f2b(v.x); a[5] = f2b(v.y); a[6] = f2b(v.z); a[7] = f2b(v.w);
      afr[kc] = a;
    }
  } else {
#pragma unroll
    for (int kc = 0; kc < 4; kc++) afr[kc] = (s8v)(short)0;
  }

  const short* wp = Wt + (size_t)m * 128 + quad * 8;
  s8v bfr[4][4];
#pragma unroll
  for (int nt = 0; nt < 4; nt++)
#pragma unroll
    for (int kc = 0; kc < 4; kc++)
      bfr[nt][kc] = *(const s8v*)(wp + nt * 16 * 128 + kc * 32);

  f4v acc[4] = {f4v{0,0,0,0}, f4v{0,0,0,0}, f4v{0,0,0,0}, f4v{0,0,0,0}};
#pragma unroll
  for (int kc = 0; kc < 4; kc++)
#pragma unroll
    for (int nt = 0; nt < 4; nt++)
      acc[nt] = __builtin_amdgcn_mfma_f32_16x16x32_bf16(afr[kc], bfr[nt][kc], acc[nt], 0, 0, 0);

  int rbase = blockIdx.x * 64 + wave * 16 + quad * 4;
#pragma unroll
  for (int reg = 0; reg < 4; reg++) {
    int rr = rbase + reg;
    if (rr < n) {
      float dv = dinv[rr];
#pragma unroll
      for (int nt = 0; nt < 4; nt++)
        g1[(size_t)rr * 64 + nt * 16 + m] = __float2bfloat16(acc[nt][reg] * dv);
    }
  }
}

// ---- MFMA gemm2: g2[n,32] = dinv[r]*(z1b[n,64] @ W2[64,32]), bf16 out ----
__global__ __launch_bounds__(256) void k_gemm2(const bf16* __restrict__ z1b,
                                               const short* __restrict__ Wt,  // [32][64] bf16
                                               const float* __restrict__ dinv,
                                               short* __restrict__ g2, int n) {
  int wave = threadIdx.x >> 6;
  int lane = threadIdx.x & 63;
  int m = lane & 15;
  int quad = lane >> 4;
  int r = blockIdx.x * 64 + wave * 16 + m;

  s8v afr[2];
  if (r < n) {
    const short* ap = (const short*)z1b + (size_t)r * 64 + quad * 8;
#pragma unroll
    for (int kc = 0; kc < 2; kc++) afr[kc] = *(const s8v*)(ap + kc * 32);
  } else {
#pragma unroll
    for (int kc = 0; kc < 2; kc++) afr[kc] = (s8v)(short)0;
  }

  const short* wp = Wt + (size_t)m * 64 + quad * 8;
  s8v bfr[2][2];
#pragma unroll
  for (int nt = 0; nt < 2; nt++)
#pragma unroll
    for (int kc = 0; kc < 2; kc++)
      bfr[nt][kc] = *(const s8v*)(wp + nt * 16 * 64 + kc * 32);

  f4v acc[2] = {f4v{0,0,0,0}, f4v{0,0,0,0}};
#pragma unroll
  for (int kc = 0; kc < 2; kc++)
#pragma unroll
    for (int nt = 0; nt < 2; nt++)
      acc[nt] = __builtin_amdgcn_mfma_f32_16x16x32_bf16(afr[kc], bfr[nt][kc], acc[nt], 0, 0, 0);

  int rbase = blockIdx.x * 64 + wave * 16 + quad * 4;
#pragma unroll
  for (int reg = 0; reg < 4; reg++) {
    int rr = rbase + reg;
    if (rr < n) {
      float dv = dinv[rr];
#pragma unroll
      for (int nt = 0; nt < 2; nt++)
        g2[(size_t)rr * 32 + nt * 16 + m] = f2b(acc[nt][reg] * dv);
    }
  }
}

// ---- layer-1 aggregate: 1 wave/dest, 8 lanes x 16B per edge (8 edges/inst) ----
// z1b[c,:] = relu(dinv[c]*(g1[c,:] + sum g1[r,:]) + b1)   (bf16 out)
__global__ __launch_bounds__(256) void k_gagg1(const int* __restrict__ row_start,
                                               const int* __restrict__ adj,
                                               const float* __restrict__ dinv,
                                               const short* __restrict__ g,   // g1 bf16 [n][64]
                                               const float* __restrict__ bias,
                                               short* __restrict__ z, int n) {
  int wave = threadIdx.x >> 6;
  int lane = threadIdx.x & 63;
  int grp = lane >> 3;     // 0..7: edge slot
  int fl = lane & 7;       // feature slice: shorts fl*8..fl*8+7 (16 B)
  int c = blockIdx.x * 4 + wave;
  if (c >= n) return;
  int start = row_start[c], end = row_start[c + 1];
  float4 a0 = {0.f,0.f,0.f,0.f}, a1 = {0.f,0.f,0.f,0.f};
  int j = start;
  for (; j + 32 <= end; j += 32) {      // 32 edges (4 KB) in flight per iter
#pragma unroll
    for (int u = 0; u < 4; u++) {
      int r = adj[j + u * 8 + grp];
      int4 pk = *(const int4*)(g + r * 64 + fl * 8);
      bf4_acc(pk.x, pk.y, a0);
      bf4_acc(pk.z, pk.w, a1);
    }
  }
  for (; j < end; j += 8) {
    int e = j + grp;
    if (e < end) {
      int r = adj[e];
      int4 pk = *(const int4*)(g + r * 64 + fl * 8);
      bf4_acc(pk.x, pk.y, a0);
      bf4_acc(pk.z, pk.w, a1);
    }
  }
  // reduce 8 edge slots (lane bits 3..5)
#pragma unroll
  for (int s = 8; s <= 32; s <<= 1) {
    a0.x += __shfl_xor(a0.x, s); a0.y += __shfl_xor(a0.y, s);
    a0.z += __shfl_xor(a0.z, s); a0.w += __shfl_xor(a0.w, s);
    a1.x += __shfl_xor(a1.x, s); a1.y += __shfl_xor(a1.y, s);
    a1.z += __shfl_xor(a1.z, s); a1.w += __shfl_xor(a1.w, s);
  }
  if (grp == 0) {
    int4 pk = *(const int4*)(g + c * 64 + fl * 8);   // self-loop
    bf4_acc(pk.x, pk.y, a0);
    bf4_acc(pk.z, pk.w, a1);
    float d = dinv[c];
    float4 b0 = *(const float4*)(bias + fl * 8);
    float4 b1 = *(const float4*)(bias + fl * 8 + 4);
    float v0 = fmaxf(fmaf(d, a0.x, b0.x), 0.f);
    float v1 = fmaxf(fmaf(d, a0.y, b0.y), 0.f);
    float v2 = fmaxf(fmaf(d, a0.z, b0.z), 0.f);
    float v3 = fmaxf(fmaf(d, a0.w, b0.w), 0.f);
    float v4 = fmaxf(fmaf(d, a1.x, b1.x), 0.f);
    float v5 = fmaxf(fmaf(d, a1.y, b1.y), 0.f);
    float v6 = fmaxf(fmaf(d, a1.z, b1.z), 0.f);
    float v7 = fmaxf(fmaf(d, a1.w, b1.w), 0.f);
    int4 out;
    out.x = (int)(unsigned short)f2b(v0) | ((int)f2b(v1) << 16);
    out.y = (int)(unsigned short)f2b(v2) | ((int)f2b(v3) << 16);
    out.z = (int)(unsigned short)f2b(v4) | ((int)f2b(v5) << 16);
    out.w = (int)(unsigned short)f2b(v6) | ((int)f2b(v7) << 16);
    *(int4*)(z + c * 64 + fl * 8) = out;
  }
}

// ---- layer-2 aggregate: 1 wave/dest, 4 lanes x 16B per edge (16 edges/inst) ----
// z2[c,:] = dinv[c]*(g2[c,:] + sum g2[r,:]) + b2   (f32 out)
__global__ __launch_bounds__(256) void k_gagg2(const int* __restrict__ row_start,
                                               const int* __restrict__ adj,
                                               const float* __restrict__ dinv,
                                               const short* __restrict__ g,   // g2 bf16 [n][32]
                                               const float* __restrict__ bias,
                                               float* __restrict__ z, int n) {
  int wave = threadIdx.x >> 6;
  int lane = threadIdx.x & 63;
  int grp = lane >> 2;     // 0..15: edge slot
  int fl = lane & 3;       // feature slice: shorts fl*8..fl*8+7 (16 B)
  int c = blockIdx.x * 4 + wave;
  if (c >= n) return;
  int start = row_start[c], end = row_start[c + 1];
  float4 a0 = {0.f,0.f,0.f,0.f}, a1 = {0.f,0.f,0.f,0.f};
  int j = start;
  for (; j + 32 <= end; j += 32) {      // 32 edges (2 KB) in flight per iter
#pragma unroll
    for (int u = 0; u < 2; u++) {
      int r = adj[j + u * 16 + grp];
      int4 pk = *(const int4*)(g + r * 32 + fl * 8);
      bf4_acc(pk.x, pk.y, a0);
      bf4_acc(pk.z, pk.w, a1);
    }
  }
  for (; j < end; j += 16) {
    int e = j + grp;
    if (e < end) {
      int r = adj[e];
      int4 pk = *(const int4*)(g + r * 32 + fl * 8);
      bf4_acc(pk.x, pk.y, a0);
      bf4_acc(pk.z, pk.w, a1);
    }
  }
  // reduce 16 edge slots (lane bits 2..5)
#pragma unroll
  for (int s = 4; s <= 32; s <<= 1) {
    a0.x += __shfl_xor(a0.x, s); a0.y += __shfl_xor(a0.y, s);
    a0.z += __shfl_xor(a0.z, s); a0.w += __shfl_xor(a0.w, s);
    a1.x += __shfl_xor(a1.x, s); a1.y += __shfl_xor(a1.y, s);
    a1.z += __shfl_xor(a1.z, s); a1.w += __shfl_xor(a1.w, s);
  }
  if (grp == 0) {
    int4 pk = *(const int4*)(g + c * 32 + fl * 8);   // self-loop
    bf4_acc(pk.x, pk.y, a0);
    bf4_acc(pk.z, pk.w, a1);
    float d = dinv[c];
    float4 b0 = *(const float4*)(bias + fl * 8);
    float4 b1 = *(const float4*)(bias + fl * 8 + 4);
    float4 o0, o1;
    o0.x = fmaf(d, a0.x, b0.x); o0.y = fmaf(d, a0.y, b0.y);
    o0.z = fmaf(d, a0.z, b0.z); o0.w = fmaf(d, a0.w, b0.w);
    o1.x = fmaf(d, a1.x, b1.x); o1.y = fmaf(d, a1.y, b1.y);
    o1.z = fmaf(d, a1.z, b1.z); o1.w = fmaf(d, a1.w, b1.w);
    *(float4*)(z + c * 32 + fl * 8) = o0;
    *(float4*)(z + c * 32 + fl * 8 + 4) = o1;
  }
}

// ---- link decode: half-wave per label edge, shuffle reduce, fp32 out ----
__global__ __launch_bounds__(256) void k_decode(const int* __restrict__ ea,
                                                const int* __restrict__ eb,
                                                const float* __restrict__ z2,
                                                float* __restrict__ out, int EL) {
  int lane = threadIdx.x & 31;
  int e = blockIdx.x * 8 + (threadIdx.x >> 5);
  if (e >= EL) return;
  int a = ea[e], b = eb[e];
  float p = z2[a * 32 + lane] * z2[b * 32 + lane];
  p += __shfl_down(p, 16);
  p += __shfl_down(p, 8);
  p += __shfl_down(p, 4);
  p += __shfl_down(p, 2);
  p += __shfl_down(p, 1);
  if (lane == 0) out[e] = p;
}

extern "C" void kernel_launch(void* const* d_in, const int* in_sizes, int n_in,
                              void* d_out, int out_size, void* d_ws, size_t ws_size,
                              hipStream_t stream) {
  const float* x   = (const float*)d_in[0];
  const float* W1  = (const float*)d_in[1];
  const float* b1  = (const float*)d_in[2];
  const float* W2  = (const float*)d_in[3];
  const float* b2  = (const float*)d_in[4];
  const int*   ei  = (const int*)d_in[5];   // [2,E]: row=ei[0..E), col=ei[E..2E)
  const int*   eli = (const int*)d_in[6];   // [2,EL]

  const int N  = in_sizes[0] / 128;  // 100000
  const int E  = in_sizes[5] / 2;    // 3200000
  const int EL = in_sizes[6] / 2;    // 200000
  const int* row = ei;
  const int* col = ei + E;
  const int NBUCK = (N + BNODES - 1) / BNODES;   // 391
  const int NCHNK = (E + CHUNK - 1) / CHUNK;     // 782

  // workspace (~60 MB)
  char* ws = (char*)d_ws;
  size_t off = 0;
  auto take = [&](size_t bytes) { char* p = ws + off; off += (bytes + 255) & ~(size_t)255; return p; };
  float* dinv      = (float*)take((size_t)N * 4);
  int*   row_start = (int*)take((size_t)(N + 1) * 4);
  int*   btot      = (int*)take((size_t)NBUCK * 4);
  int*   bbase     = (int*)take((size_t)(NBUCK + 1) * 4);
  short* Wt1       = (short*)take((size_t)64 * 128 * 2);
  short* Wt2       = (short*)take((size_t)32 * 64 * 2);
  int*   chist     = (int*)take((size_t)NCHNK * NBUCK * 4);   // 1.22 MB
  int*   adjTmp    = (int*)take((size_t)E * 4);               // 12.8 MB
  int*   adj       = (int*)take((size_t)E * 4);               // 12.8 MB
  char*  bufH      = take((size_t)N * 64 * 2);                // g1 bf16 / g2 bf16
  short* z1b       = (short*)take((size_t)N * 64 * 2);        // relu'd, bf16
  float* z2        = (float*)take((size_t)N * 32 * 4);
  (void)ws_size; (void)n_in; (void)out_size;

  bf16*  g1 = (bf16*)bufH;
  short* g2 = (short*)bufH;   // aliases g1 (g1 dead when g2 written)

  k_prepW     <<<32, 256, 0, stream>>>(W1, W2, Wt1, Wt2);
  k_hist      <<<NCHNK, 256, 0, stream>>>(col, E, NBUCK, chist);
  k_scanbuck  <<<NBUCK, 256, 0, stream>>>(chist, NCHNK, NBUCK, btot);
  k_scanbase  <<<1, 64, 0, stream>>>(btot, NBUCK, bbase, row_start, N);
  k_binpass   <<<NCHNK, 256, 0, stream>>>(row, col, E, NBUCK, bbase, chist, adjTmp);
  k_bucketsort<<<NBUCK, 256, 0, stream>>>(bbase, adjTmp, adj, row_start, dinv, N);

  k_gemm1<<<(N + 63) / 64, 256, 0, stream>>>(x, Wt1, dinv, g1, N);
  k_gagg1<<<(N + 3) / 4, 256, 0, stream>>>(row_start, adj, dinv, (const short*)g1, b1, z1b, N);

  k_gemm2<<<(N + 63) / 64, 256, 0, stream>>>((const bf16*)z1b, Wt2, dinv, g2, N);
  k_gagg2<<<(N + 3) / 4, 256, 0, stream>>>(row_start, adj, dinv, g2, b2, z2, N);

  k_decode<<<(EL + 7) / 8, 256, 0, stream>>>(eli, eli + EL, z2, (float*)d_out, EL);
}

// Round 10
// 312.475 us; speedup vs baseline: 4.6936x; 1.0338x over previous
//
#include <hip/hip_runtime.h>
#include <hip/hip_bf16.h>

typedef __hip_bfloat16 bf16;
typedef short s8v __attribute__((ext_vector_type(8)));   // 8 bf16 in 4 VGPRs
typedef float f4v __attribute__((ext_vector_type(4)));   // MFMA 16x16 C/D frag

__device__ __forceinline__ short f2b(float f) {
  bf16 h = __float2bfloat16(f);
  return *reinterpret_cast<short*>(&h);
}
// accumulate 4 bf16 (packed in 2 dwords, memory order) into float4
__device__ __forceinline__ void bf4_acc(int lo, int hi, float4& a) {
  a.x += __int_as_float(lo << 16);
  a.y += __int_as_float(lo & 0xFFFF0000);
  a.z += __int_as_float(hi << 16);
  a.w += __int_as_float(hi & 0xFFFF0000);
}

#define BSHIFT 8        // 256 dest nodes per bucket
#define BNODES 256
#define CHUNK 4096      // edges per chunk
#define SORT_CAP 12288  // bucket-sort LDS capacity (48 KB); mean bucket = 8192

// ---- phase 1: per-chunk bucket histogram (LDS atomics only) ----
__global__ __launch_bounds__(256) void k_hist(const int* __restrict__ col, int E,
                                              int nbuck, int* __restrict__ chist) {
  __shared__ int hist[512];
  int t = threadIdx.x;
  hist[t] = 0; hist[t + 256] = 0;
  __syncthreads();
  int e0 = blockIdx.x * CHUNK;
#pragma unroll
  for (int i = 0; i < 16; i++) {
    int e = e0 + i * 256 + t;
    if (e < E) atomicAdd(&hist[col[e] >> BSHIFT], 1);
  }
  __syncthreads();
  int* out = chist + (size_t)blockIdx.x * nbuck;
  for (int b = t; b < nbuck; b += 256) out[b] = hist[b];  // coalesced
}

// ---- phase 2: per-bucket exclusive scan over chunks (in place) ----
__global__ __launch_bounds__(256) void k_scanbuck(int* __restrict__ chist, int nchnk,
                                                  int nbuck, int* __restrict__ btot) {
  __shared__ int sm[256];
  int b = blockIdx.x, t = threadIdx.x;
  int per = (nchnk + 255) / 256;
  int lo = t * per, hi = min(lo + per, nchnk);
  int s = 0;
  for (int i = lo; i < hi; i++) s += chist[(size_t)i * nbuck + b];
  sm[t] = s;
  __syncthreads();
  for (int d = 1; d < 256; d <<= 1) {
    int x = (t >= d) ? sm[t - d] : 0;
    __syncthreads();
    sm[t] += x;
    __syncthreads();
  }
  int off = (t == 0) ? 0 : sm[t - 1];
  for (int i = lo; i < hi; i++) {
    int c = chist[(size_t)i * nbuck + b];
    chist[(size_t)i * nbuck + b] = off;
    off += c;
  }
  if (t == 255) btot[b] = sm[255];
}

// ---- phase 3: scan bucket totals — PARALLEL LDS scan (was serial 1-thread,
// ~400-600 dependent-load cycles x 391 iters = tens of µs hidden cost) ----
__global__ __launch_bounds__(512) void k_scanbase(const int* __restrict__ btot, int nbuck,
                                                  int* __restrict__ bbase,
                                                  int* __restrict__ row_start, int n) {
  __shared__ int sm[512];
  int t = threadIdx.x;
  int v = (t < nbuck) ? btot[t] : 0;
  sm[t] = v;
  __syncthreads();
  for (int d = 1; d < 512; d <<= 1) {   // Hillis-Steele inclusive
    int x = (t >= d) ? sm[t - d] : 0;
    __syncthreads();
    sm[t] += x;
    __syncthreads();
  }
  if (t < nbuck) bbase[t] = sm[t] - v;  // exclusive prefix
  if (t == nbuck - 1) {
    bbase[nbuck] = sm[t];
    row_start[n] = sm[t];  // == E
  }
}

// ---- phase 4: grouped scatter into bucket-sorted adjTmp, NO global atomics ----
// adjTmp entry: r | (c_low << 17)
__global__ __launch_bounds__(256) void k_binpass(const int* __restrict__ row,
                                                 const int* __restrict__ col, int E,
                                                 int nbuck,
                                                 const int* __restrict__ bbase,
                                                 const int* __restrict__ chist,
                                                 int* __restrict__ adjTmp) {
  __shared__ int hist[512];
  __shared__ int base[512];
  __shared__ int lcur[512];
  __shared__ int gbase[512];
  __shared__ int psum[256];
  __shared__ int stage[CHUNK];
  __shared__ unsigned short sbkt[CHUNK];
  __shared__ int s_total;
  int t = threadIdx.x;
  int e0 = blockIdx.x * CHUNK;

  hist[t] = 0; hist[t + 256] = 0;
  __syncthreads();

  int pk[16], bk[16];
#pragma unroll
  for (int i = 0; i < 16; i++) {
    int e = e0 + i * 256 + t;
    if (e < E) {
      int c = col[e];
      int r = row[e];
      bk[i] = c >> BSHIFT;
      pk[i] = r | ((c & (BNODES - 1)) << 17);
      atomicAdd(&hist[bk[i]], 1);
    } else bk[i] = -1;
  }
  __syncthreads();
  int a0 = hist[2 * t], a1 = hist[2 * t + 1];
  psum[t] = a0 + a1;
  __syncthreads();
  for (int d = 1; d < 256; d <<= 1) {
    int v = (t >= d) ? psum[t - d] : 0;
    __syncthreads();
    psum[t] += v;
    __syncthreads();
  }
  int pref = (t == 0) ? 0 : psum[t - 1];
  base[2 * t] = pref;          lcur[2 * t] = pref;
  base[2 * t + 1] = pref + a0; lcur[2 * t + 1] = pref + a0;
  if (t == 255) s_total = psum[255];
  const int* coff = chist + (size_t)blockIdx.x * nbuck;
  for (int b = t; b < nbuck; b += 256) gbase[b] = bbase[b] + coff[b];
  __syncthreads();
#pragma unroll
  for (int i = 0; i < 16; i++) {
    if (bk[i] >= 0) {
      int pos = atomicAdd(&lcur[bk[i]], 1);
      stage[pos] = pk[i];
      sbkt[pos] = (unsigned short)bk[i];
    }
  }
  __syncthreads();
  int total = s_total;
  for (int i = t; i < total; i += 256) {
    int b = sbkt[i];
    adjTmp[gbase[b] + (i - base[b])] = stage[i];
  }
}

// ---- phase 5: per-bucket sort; emits deg->dinv, row_start, sorted adj ----
__global__ __launch_bounds__(256) void k_bucketsort(const int* __restrict__ bbase,
                                                    const int* __restrict__ adjTmp,
                                                    int* __restrict__ adj,
                                                    int* __restrict__ row_start,
                                                    float* __restrict__ dinv, int n) {
  __shared__ int cnt[BNODES];
  __shared__ int sc[BNODES];
  __shared__ int cur[BNODES];
  __shared__ int stage[SORT_CAP];
  int b = blockIdx.x, t = threadIdx.x;
  int node_base = b << BSHIFT;
  int nnode = min(BNODES, n - node_base);
  int seg_base = bbase[b];
  int cntE = bbase[b + 1] - seg_base;
  cnt[t] = 0;
  __syncthreads();
  for (int i = t; i < cntE; i += 256) atomicAdd(&cnt[adjTmp[seg_base + i] >> 17], 1);
  __syncthreads();
  int myc = cnt[t];
  sc[t] = myc;
  __syncthreads();
  for (int d = 1; d < 256; d <<= 1) {
    int x = (t >= d) ? sc[t - d] : 0;
    __syncthreads();
    sc[t] += x;
    __syncthreads();
  }
  int excl = (t == 0) ? 0 : sc[t - 1];
  cur[t] = excl;
  if (t < nnode) {
    row_start[node_base + t] = seg_base + excl;
    dinv[node_base + t] = rsqrtf((float)myc + 1.0f);  // +1 = self-loop
  }
  __syncthreads();
  if (cntE <= SORT_CAP) {
    for (int i = t; i < cntE; i += 256) {
      int p = adjTmp[seg_base + i];
      int pos = atomicAdd(&cur[p >> 17], 1);
      stage[pos] = p & 0x1FFFF;
    }
    __syncthreads();
    for (int i = t; i < cntE; i += 256) adj[seg_base + i] = stage[i];
  } else {
    for (int i = t; i < cntE; i += 256) {
      int p = adjTmp[seg_base + i];
      int pos = atomicAdd(&cur[p >> 17], 1);
      adj[seg_base + pos] = p & 0x1FFFF;
    }
  }
}

// ---- weight prep: Wt1[64][128] = W1^T bf16, Wt2[32][64] = W2^T bf16 ----
__global__ __launch_bounds__(256) void k_prepW(const float* __restrict__ W1,
                                               const float* __restrict__ W2,
                                               short* __restrict__ Wt1,
                                               short* __restrict__ Wt2) {
  int t = blockIdx.x * 256 + threadIdx.x;
  if (t < 128 * 64) { int k = t >> 6, c = t & 63; Wt1[c * 128 + k] = f2b(W1[t]); }
  if (t < 64 * 32)  { int k = t >> 5, c = t & 31; Wt2[c * 64 + k] = f2b(W2[t]); }
}

// ---- MFMA gemm1: g1[n,64] = dinv[r]*(x[n,128] @ W1[128,64]), bf16 out ----
__global__ __launch_bounds__(256) void k_gemm1(const float* __restrict__ x,
                                               const short* __restrict__ Wt,  // [64][128] bf16
                                               const float* __restrict__ dinv,
                                               bf16* __restrict__ g1, int n) {
  int wave = threadIdx.x >> 6;
  int lane = threadIdx.x & 63;
  int m = lane & 15;
  int quad = lane >> 4;
  int r = blockIdx.x * 64 + wave * 16 + m;

  s8v afr[4];
  if (r < n) {
    const float* ap = x + (size_t)r * 128 + quad * 8;
#pragma unroll
    for (int kc = 0; kc < 4; kc++) {
      float4 u = *(const float4*)(ap + kc * 32);
      float4 v = *(const float4*)(ap + kc * 32 + 4);
      s8v a;
      a[0] = f2b(u.x); a[1] = f2b(u.y); a[2] = f2b(u.z); a[3] = f2b(u.w);
      a[4] = f2b(v.x); a[5] = f2b(v.y); a[6] = f2b(v.z); a[7] = f2b(v.w);
      afr[kc] = a;
    }
  } else {
#pragma unroll
    for (int kc = 0; kc < 4; kc++) afr[kc] = (s8v)(short)0;
  }

  const short* wp = Wt + (size_t)m * 128 + quad * 8;
  s8v bfr[4][4];
#pragma unroll
  for (int nt = 0; nt < 4; nt++)
#pragma unroll
    for (int kc = 0; kc < 4; kc++)
      bfr[nt][kc] = *(const s8v*)(wp + nt * 16 * 128 + kc * 32);

  f4v acc[4] = {f4v{0,0,0,0}, f4v{0,0,0,0}, f4v{0,0,0,0}, f4v{0,0,0,0}};
#pragma unroll
  for (int kc = 0; kc < 4; kc++)
#pragma unroll
    for (int nt = 0; nt < 4; nt++)
      acc[nt] = __builtin_amdgcn_mfma_f32_16x16x32_bf16(afr[kc], bfr[nt][kc], acc[nt], 0, 0, 0);

  int rbase = blockIdx.x * 64 + wave * 16 + quad * 4;
#pragma unroll
  for (int reg = 0; reg < 4; reg++) {
    int rr = rbase + reg;
    if (rr < n) {
      float dv = dinv[rr];
#pragma unroll
      for (int nt = 0; nt < 4; nt++)
        g1[(size_t)rr * 64 + nt * 16 + m] = __float2bfloat16(acc[nt][reg] * dv);
    }
  }
}

// ---- MFMA gemm2: g2[n,32] = dinv[r]*(z1b[n,64] @ W2[64,32]), bf16 out ----
__global__ __launch_bounds__(256) void k_gemm2(const bf16* __restrict__ z1b,
                                               const short* __restrict__ Wt,  // [32][64] bf16
                                               const float* __restrict__ dinv,
                                               short* __restrict__ g2, int n) {
  int wave = threadIdx.x >> 6;
  int lane = threadIdx.x & 63;
  int m = lane & 15;
  int quad = lane >> 4;
  int r = blockIdx.x * 64 + wave * 16 + m;

  s8v afr[2];
  if (r < n) {
    const short* ap = (const short*)z1b + (size_t)r * 64 + quad * 8;
#pragma unroll
    for (int kc = 0; kc < 2; kc++) afr[kc] = *(const s8v*)(ap + kc * 32);
  } else {
#pragma unroll
    for (int kc = 0; kc < 2; kc++) afr[kc] = (s8v)(short)0;
  }

  const short* wp = Wt + (size_t)m * 64 + quad * 8;
  s8v bfr[2][2];
#pragma unroll
  for (int nt = 0; nt < 2; nt++)
#pragma unroll
    for (int kc = 0; kc < 2; kc++)
      bfr[nt][kc] = *(const s8v*)(wp + nt * 16 * 64 + kc * 32);

  f4v acc[2] = {f4v{0,0,0,0}, f4v{0,0,0,0}};
#pragma unroll
  for (int kc = 0; kc < 2; kc++)
#pragma unroll
    for (int nt = 0; nt < 2; nt++)
      acc[nt] = __builtin_amdgcn_mfma_f32_16x16x32_bf16(afr[kc], bfr[nt][kc], acc[nt], 0, 0, 0);

  int rbase = blockIdx.x * 64 + wave * 16 + quad * 4;
#pragma unroll
  for (int reg = 0; reg < 4; reg++) {
    int rr = rbase + reg;
    if (rr < n) {
      float dv = dinv[rr];
#pragma unroll
      for (int nt = 0; nt < 2; nt++)
        g2[(size_t)rr * 32 + nt * 16 + m] = f2b(acc[nt][reg] * dv);
    }
  }
}

// ---- layer-1 aggregate: 1 wave/dest, 8 lanes x 16B per edge (8 edges/inst),
//      2-stage software pipeline: next 32-edge group issued before consuming ----
__global__ __launch_bounds__(256) void k_gagg1(const int* __restrict__ row_start,
                                               const int* __restrict__ adj,
                                               const float* __restrict__ dinv,
                                               const short* __restrict__ g,   // g1 bf16 [n][64]
                                               const float* __restrict__ bias,
                                               short* __restrict__ z, int n) {
  int wave = threadIdx.x >> 6;
  int lane = threadIdx.x & 63;
  int grp = lane >> 3;     // 0..7: edge slot
  int fl = lane & 7;       // feature slice: shorts fl*8..fl*8+7 (16 B)
  int c = blockIdx.x * 4 + wave;
  if (c >= n) return;
  int start = row_start[c], end = row_start[c + 1];
  float4 a0 = {0.f,0.f,0.f,0.f}, a1 = {0.f,0.f,0.f,0.f};
  int nmain = ((end - start) >> 5) << 5;
  int jend = start + nmain;
  int j = start;
  if (j < jend) {
    int4 p[4];
#pragma unroll
    for (int u = 0; u < 4; u++) {
      int r = adj[j + u * 8 + grp];
      p[u] = *(const int4*)(g + r * 64 + fl * 8);
    }
    j += 32;
    for (; j < jend; j += 32) {
      int4 q[4];
#pragma unroll
      for (int u = 0; u < 4; u++) {
        int r = adj[j + u * 8 + grp];
        q[u] = *(const int4*)(g + r * 64 + fl * 8);
      }
#pragma unroll
      for (int u = 0; u < 4; u++) {
        bf4_acc(p[u].x, p[u].y, a0);
        bf4_acc(p[u].z, p[u].w, a1);
        p[u] = q[u];
      }
    }
#pragma unroll
    for (int u = 0; u < 4; u++) {
      bf4_acc(p[u].x, p[u].y, a0);
      bf4_acc(p[u].z, p[u].w, a1);
    }
  }
  for (; j < end; j += 8) {
    int e = j + grp;
    if (e < end) {
      int r = adj[e];
      int4 pk = *(const int4*)(g + r * 64 + fl * 8);
      bf4_acc(pk.x, pk.y, a0);
      bf4_acc(pk.z, pk.w, a1);
    }
  }
  // reduce 8 edge slots (lane bits 3..5)
#pragma unroll
  for (int s = 8; s <= 32; s <<= 1) {
    a0.x += __shfl_xor(a0.x, s); a0.y += __shfl_xor(a0.y, s);
    a0.z += __shfl_xor(a0.z, s); a0.w += __shfl_xor(a0.w, s);
    a1.x += __shfl_xor(a1.x, s); a1.y += __shfl_xor(a1.y, s);
    a1.z += __shfl_xor(a1.z, s); a1.w += __shfl_xor(a1.w, s);
  }
  if (grp == 0) {
    int4 pk = *(const int4*)(g + c * 64 + fl * 8);   // self-loop
    bf4_acc(pk.x, pk.y, a0);
    bf4_acc(pk.z, pk.w, a1);
    float d = dinv[c];
    float4 b0 = *(const float4*)(bias + fl * 8);
    float4 b1 = *(const float4*)(bias + fl * 8 + 4);
    float v0 = fmaxf(fmaf(d, a0.x, b0.x), 0.f);
    float v1 = fmaxf(fmaf(d, a0.y, b0.y), 0.f);
    float v2 = fmaxf(fmaf(d, a0.z, b0.z), 0.f);
    float v3 = fmaxf(fmaf(d, a0.w, b0.w), 0.f);
    float v4 = fmaxf(fmaf(d, a1.x, b1.x), 0.f);
    float v5 = fmaxf(fmaf(d, a1.y, b1.y), 0.f);
    float v6 = fmaxf(fmaf(d, a1.z, b1.z), 0.f);
    float v7 = fmaxf(fmaf(d, a1.w, b1.w), 0.f);
    int4 out;
    out.x = (int)(unsigned short)f2b(v0) | ((int)f2b(v1) << 16);
    out.y = (int)(unsigned short)f2b(v2) | ((int)f2b(v3) << 16);
    out.z = (int)(unsigned short)f2b(v4) | ((int)f2b(v5) << 16);
    out.w = (int)(unsigned short)f2b(v6) | ((int)f2b(v7) << 16);
    *(int4*)(z + c * 64 + fl * 8) = out;
  }
}

// ---- layer-2 aggregate: 1 wave/dest, 4 lanes x 16B per edge (16 edges/inst),
//      2-stage software pipeline ----
__global__ __launch_bounds__(256) void k_gagg2(const int* __restrict__ row_start,
                                               const int* __restrict__ adj,
                                               const float* __restrict__ dinv,
                                               const short* __restrict__ g,   // g2 bf16 [n][32]
                                               const float* __restrict__ bias,
                                               float* __restrict__ z, int n) {
  int wave = threadIdx.x >> 6;
  int lane = threadIdx.x & 63;
  int grp = lane >> 2;     // 0..15: edge slot
  int fl = lane & 3;       // feature slice: shorts fl*8..fl*8+7 (16 B)
  int c = blockIdx.x * 4 + wave;
  if (c >= n) return;
  int start = row_start[c], end = row_start[c + 1];
  float4 a0 = {0.f,0.f,0.f,0.f}, a1 = {0.f,0.f,0.f,0.f};
  int nmain = ((end - start) >> 5) << 5;
  int jend = start + nmain;
  int j = start;
  if (j < jend) {
    int4 p[2];
#pragma unroll
    for (int u = 0; u < 2; u++) {
      int r = adj[j + u * 16 + grp];
      p[u] = *(const int4*)(g + r * 32 + fl * 8);
    }
    j += 32;
    for (; j < jend; j += 32) {
      int4 q[2];
#pragma unroll
      for (int u = 0; u < 2; u++) {
        int r = adj[j + u * 16 + grp];
        q[u] = *(const int4*)(g + r * 32 + fl * 8);
      }
#pragma unroll
      for (int u = 0; u < 2; u++) {
        bf4_acc(p[u].x, p[u].y, a0);
        bf4_acc(p[u].z, p[u].w, a1);
        p[u] = q[u];
      }
    }
#pragma unroll
    for (int u = 0; u < 2; u++) {
      bf4_acc(p[u].x, p[u].y, a0);
      bf4_acc(p[u].z, p[u].w, a1);
    }
  }
  for (; j < end; j += 16) {
    int e = j + grp;
    if (e < end) {
      int r = adj[e];
      int4 pk = *(const int4*)(g + r * 32 + fl * 8);
      bf4_acc(pk.x, pk.y, a0);
      bf4_acc(pk.z, pk.w, a1);
    }
  }
  // reduce 16 edge slots (lane bits 2..5)
#pragma unroll
  for (int s = 4; s <= 32; s <<= 1) {
    a0.x += __shfl_xor(a0.x, s); a0.y += __shfl_xor(a0.y, s);
    a0.z += __shfl_xor(a0.z, s); a0.w += __shfl_xor(a0.w, s);
    a1.x += __shfl_xor(a1.x, s); a1.y += __shfl_xor(a1.y, s);
    a1.z += __shfl_xor(a1.z, s); a1.w += __shfl_xor(a1.w, s);
  }
  if (grp == 0) {
    int4 pk = *(const int4*)(g + c * 32 + fl * 8);   // self-loop
    bf4_acc(pk.x, pk.y, a0);
    bf4_acc(pk.z, pk.w, a1);
    float d = dinv[c];
    float4 b0 = *(const float4*)(bias + fl * 8);
    float4 b1 = *(const float4*)(bias + fl * 8 + 4);
    float4 o0, o1;
    o0.x = fmaf(d, a0.x, b0.x); o0.y = fmaf(d, a0.y, b0.y);
    o0.z = fmaf(d, a0.z, b0.z); o0.w = fmaf(d, a0.w, b0.w);
    o1.x = fmaf(d, a1.x, b1.x); o1.y = fmaf(d, a1.y, b1.y);
    o1.z = fmaf(d, a1.z, b1.z); o1.w = fmaf(d, a1.w, b1.w);
    *(float4*)(z + c * 32 + fl * 8) = o0;
    *(float4*)(z + c * 32 + fl * 8 + 4) = o1;
  }
}

// ---- link decode: half-wave per label edge, shuffle reduce, fp32 out ----
__global__ __launch_bounds__(256) void k_decode(const int* __restrict__ ea,
                                                const int* __restrict__ eb,
                                                const float* __restrict__ z2,
                                                float* __restrict__ out, int EL) {
  int lane = threadIdx.x & 31;
  int e = blockIdx.x * 8 + (threadIdx.x >> 5);
  if (e >= EL) return;
  int a = ea[e], b = eb[e];
  float p = z2[a * 32 + lane] * z2[b * 32 + lane];
  p += __shfl_down(p, 16);
  p += __shfl_down(p, 8);
  p += __shfl_down(p, 4);
  p += __shfl_down(p, 2);
  p += __shfl_down(p, 1);
  if (lane == 0) out[e] = p;
}

extern "C" void kernel_launch(void* const* d_in, const int* in_sizes, int n_in,
                              void* d_out, int out_size, void* d_ws, size_t ws_size,
                              hipStream_t stream) {
  const float* x   = (const float*)d_in[0];
  const float* W1  = (const float*)d_in[1];
  const float* b1  = (const float*)d_in[2];
  const float* W2  = (const float*)d_in[3];
  const float* b2  = (const float*)d_in[4];
  const int*   ei  = (const int*)d_in[5];   // [2,E]: row=ei[0..E), col=ei[E..2E)
  const int*   eli = (const int*)d_in[6];   // [2,EL]

  const int N  = in_sizes[0] / 128;  // 100000
  const int E  = in_sizes[5] / 2;    // 3200000
  const int EL = in_sizes[6] / 2;    // 200000
  const int* row = ei;
  const int* col = ei + E;
  const int NBUCK = (N + BNODES - 1) / BNODES;   // 391
  const int NCHNK = (E + CHUNK - 1) / CHUNK;     // 782

  // workspace (~60 MB)
  char* ws = (char*)d_ws;
  size_t off = 0;
  auto take = [&](size_t bytes) { char* p = ws + off; off += (bytes + 255) & ~(size_t)255; return p; };
  float* dinv      = (float*)take((size_t)N * 4);
  int*   row_start = (int*)take((size_t)(N + 1) * 4);
  int*   btot      = (int*)take((size_t)NBUCK * 4);
  int*   bbase     = (int*)take((size_t)(NBUCK + 1) * 4);
  short* Wt1       = (short*)take((size_t)64 * 128 * 2);
  short* Wt2       = (short*)take((size_t)32 * 64 * 2);
  int*   chist     = (int*)take((size_t)NCHNK * NBUCK * 4);   // 1.22 MB
  int*   adjTmp    = (int*)take((size_t)E * 4);               // 12.8 MB
  int*   adj       = (int*)take((size_t)E * 4);               // 12.8 MB
  char*  bufH      = take((size_t)N * 64 * 2);                // g1 bf16 / g2 bf16
  short* z1b       = (short*)take((size_t)N * 64 * 2);        // relu'd, bf16
  float* z2        = (float*)take((size_t)N * 32 * 4);
  (void)ws_size; (void)n_in; (void)out_size;

  bf16*  g1 = (bf16*)bufH;
  short* g2 = (short*)bufH;   // aliases g1 (g1 dead when g2 written)

  k_prepW     <<<32, 256, 0, stream>>>(W1, W2, Wt1, Wt2);
  k_hist      <<<NCHNK, 256, 0, stream>>>(col, E, NBUCK, chist);
  k_scanbuck  <<<NBUCK, 256, 0, stream>>>(chist, NCHNK, NBUCK, btot);
  k_scanbase  <<<1, 512, 0, stream>>>(btot, NBUCK, bbase, row_start, N);
  k_binpass   <<<NCHNK, 256, 0, stream>>>(row, col, E, NBUCK, bbase, chist, adjTmp);
  k_bucketsort<<<NBUCK, 256, 0, stream>>>(bbase, adjTmp, adj, row_start, dinv, N);

  k_gemm1<<<(N + 63) / 64, 256, 0, stream>>>(x, Wt1, dinv, g1, N);
  k_gagg1<<<(N + 3) / 4, 256, 0, stream>>>(row_start, adj, dinv, (const short*)g1, b1, z1b, N);

  k_gemm2<<<(N + 63) / 64, 256, 0, stream>>>((const bf16*)z1b, Wt2, dinv, g2, N);
  k_gagg2<<<(N + 3) / 4, 256, 0, stream>>>(row_start, adj, dinv, g2, b2, z2, N);

  k_decode<<<(EL + 7) / 8, 256, 0, stream>>>(eli, eli + EL, z2, (float*)d_out, EL);
}

// Round 11
// 307.555 us; speedup vs baseline: 4.7687x; 1.0160x over previous
//
#include <hip/hip_runtime.h>
#include <hip/hip_bf16.h>

typedef __hip_bfloat16 bf16;
typedef short s8v __attribute__((ext_vector_type(8)));   // 8 bf16 in 4 VGPRs
typedef float f4v __attribute__((ext_vector_type(4)));   // MFMA 16x16 C/D frag

__device__ __forceinline__ short f2b(float f) {
  bf16 h = __float2bfloat16(f);
  return *reinterpret_cast<short*>(&h);
}
// accumulate 4 bf16 (packed in 2 dwords, memory order) into float4
__device__ __forceinline__ void bf4_acc(int lo, int hi, float4& a) {
  a.x += __int_as_float(lo << 16);
  a.y += __int_as_float(lo & 0xFFFF0000);
  a.z += __int_as_float(hi << 16);
  a.w += __int_as_float(hi & 0xFFFF0000);
}

#define BSHIFT 8        // 256 dest nodes per bucket
#define BNODES 256
#define CHUNK 4096      // edges per chunk
#define SORT_CAP 12288  // bucket-sort LDS capacity (48 KB); mean bucket = 8192
#define TSHIFT 15       // source tile = 32K rows = 4 MB of g1 (fits per-XCD L2)

// ---- phase 1: per-chunk bucket histogram (LDS atomics only) ----
__global__ __launch_bounds__(256) void k_hist(const int* __restrict__ col, int E,
                                              int nbuck, int* __restrict__ chist) {
  __shared__ int hist[512];
  int t = threadIdx.x;
  hist[t] = 0; hist[t + 256] = 0;
  __syncthreads();
  int e0 = blockIdx.x * CHUNK;
#pragma unroll
  for (int i = 0; i < 16; i++) {
    int e = e0 + i * 256 + t;
    if (e < E) atomicAdd(&hist[col[e] >> BSHIFT], 1);
  }
  __syncthreads();
  int* out = chist + (size_t)blockIdx.x * nbuck;
  for (int b = t; b < nbuck; b += 256) out[b] = hist[b];  // coalesced
}

// ---- phase 2: per-bucket exclusive scan over chunks (in place) ----
__global__ __launch_bounds__(256) void k_scanbuck(int* __restrict__ chist, int nchnk,
                                                  int nbuck, int* __restrict__ btot) {
  __shared__ int sm[256];
  int b = blockIdx.x, t = threadIdx.x;
  int per = (nchnk + 255) / 256;
  int lo = t * per, hi = min(lo + per, nchnk);
  int s = 0;
  for (int i = lo; i < hi; i++) s += chist[(size_t)i * nbuck + b];
  sm[t] = s;
  __syncthreads();
  for (int d = 1; d < 256; d <<= 1) {
    int x = (t >= d) ? sm[t - d] : 0;
    __syncthreads();
    sm[t] += x;
    __syncthreads();
  }
  int off = (t == 0) ? 0 : sm[t - 1];
  for (int i = lo; i < hi; i++) {
    int c = chist[(size_t)i * nbuck + b];
    chist[(size_t)i * nbuck + b] = off;
    off += c;
  }
  if (t == 255) btot[b] = sm[255];
}

// ---- phase 3: scan bucket totals (parallel LDS scan) ----
__global__ __launch_bounds__(512) void k_scanbase(const int* __restrict__ btot, int nbuck,
                                                  int* __restrict__ bbase,
                                                  int* __restrict__ row_start, int n) {
  __shared__ int sm[512];
  int t = threadIdx.x;
  int v = (t < nbuck) ? btot[t] : 0;
  sm[t] = v;
  __syncthreads();
  for (int d = 1; d < 512; d <<= 1) {   // Hillis-Steele inclusive
    int x = (t >= d) ? sm[t - d] : 0;
    __syncthreads();
    sm[t] += x;
    __syncthreads();
  }
  if (t < nbuck) bbase[t] = sm[t] - v;  // exclusive prefix
  if (t == nbuck - 1) {
    bbase[nbuck] = sm[t];
    row_start[n] = sm[t];  // == E
  }
}

// ---- phase 4: grouped scatter into bucket-sorted adjTmp, NO global atomics ----
// adjTmp entry: r | (c_low << 17)
__global__ __launch_bounds__(256) void k_binpass(const int* __restrict__ row,
                                                 const int* __restrict__ col, int E,
                                                 int nbuck,
                                                 const int* __restrict__ bbase,
                                                 const int* __restrict__ chist,
                                                 int* __restrict__ adjTmp) {
  __shared__ int hist[512];
  __shared__ int base[512];
  __shared__ int lcur[512];
  __shared__ int gbase[512];
  __shared__ int psum[256];
  __shared__ int stage[CHUNK];
  __shared__ unsigned short sbkt[CHUNK];
  __shared__ int s_total;
  int t = threadIdx.x;
  int e0 = blockIdx.x * CHUNK;

  hist[t] = 0; hist[t + 256] = 0;
  __syncthreads();

  int pk[16], bk[16];
#pragma unroll
  for (int i = 0; i < 16; i++) {
    int e = e0 + i * 256 + t;
    if (e < E) {
      int c = col[e];
      int r = row[e];
      bk[i] = c >> BSHIFT;
      pk[i] = r | ((c & (BNODES - 1)) << 17);
      atomicAdd(&hist[bk[i]], 1);
    } else bk[i] = -1;
  }
  __syncthreads();
  int a0 = hist[2 * t], a1 = hist[2 * t + 1];
  psum[t] = a0 + a1;
  __syncthreads();
  for (int d = 1; d < 256; d <<= 1) {
    int v = (t >= d) ? psum[t - d] : 0;
    __syncthreads();
    psum[t] += v;
    __syncthreads();
  }
  int pref = (t == 0) ? 0 : psum[t - 1];
  base[2 * t] = pref;          lcur[2 * t] = pref;
  base[2 * t + 1] = pref + a0; lcur[2 * t + 1] = pref + a0;
  if (t == 255) s_total = psum[255];
  const int* coff = chist + (size_t)blockIdx.x * nbuck;
  for (int b = t; b < nbuck; b += 256) gbase[b] = bbase[b] + coff[b];
  __syncthreads();
#pragma unroll
  for (int i = 0; i < 16; i++) {
    if (bk[i] >= 0) {
      int pos = atomicAdd(&lcur[bk[i]], 1);
      stage[pos] = pk[i];
      sbkt[pos] = (unsigned short)bk[i];
    }
  }
  __syncthreads();
  int total = s_total;
  for (int i = t; i < total; i += 256) {
    int b = sbkt[i];
    adjTmp[gbase[b] + (i - base[b])] = stage[i];
  }
}

// ---- phase 5: per-bucket sort, key = (c_low, src_tile); emits dinv, row_start,
//      adj sorted by dest node with each row's edges ordered by 4MB source tile
//      (keeps the device's concurrent gathers within ~one L2-sized tile) ----
__global__ __launch_bounds__(256) void k_bucketsort(const int* __restrict__ bbase,
                                                    const int* __restrict__ adjTmp,
                                                    int* __restrict__ adj,
                                                    int* __restrict__ row_start,
                                                    float* __restrict__ dinv, int n) {
  __shared__ int cnt[1024];
  __shared__ int sc[256];
  __shared__ int cur[1024];
  __shared__ int stage[SORT_CAP];
  int b = blockIdx.x, t = threadIdx.x;
  int node_base = b << BSHIFT;
  int nnode = min(BNODES, n - node_base);
  int seg_base = bbase[b];
  int cntE = bbase[b + 1] - seg_base;
  cnt[t] = 0; cnt[t + 256] = 0; cnt[t + 512] = 0; cnt[t + 768] = 0;
  __syncthreads();
  for (int i = t; i < cntE; i += 256) {
    int p = adjTmp[seg_base + i];
    int key = (((p >> 17) & 255) << 2) | ((p >> TSHIFT) & 3);
    atomicAdd(&cnt[key], 1);
  }
  __syncthreads();
  int c0 = cnt[4 * t], c1 = cnt[4 * t + 1], c2 = cnt[4 * t + 2], c3 = cnt[4 * t + 3];
  int myc = c0 + c1 + c2 + c3;        // node degree
  sc[t] = myc;
  __syncthreads();
  for (int d = 1; d < 256; d <<= 1) {
    int x = (t >= d) ? sc[t - d] : 0;
    __syncthreads();
    sc[t] += x;
    __syncthreads();
  }
  int excl = (t == 0) ? 0 : sc[t - 1];
  cur[4 * t] = excl;
  cur[4 * t + 1] = excl + c0;
  cur[4 * t + 2] = excl + c0 + c1;
  cur[4 * t + 3] = excl + c0 + c1 + c2;
  if (t < nnode) {
    row_start[node_base + t] = seg_base + excl;
    dinv[node_base + t] = rsqrtf((float)myc + 1.0f);  // +1 = self-loop
  }
  __syncthreads();
  if (cntE <= SORT_CAP) {
    for (int i = t; i < cntE; i += 256) {
      int p = adjTmp[seg_base + i];
      int key = (((p >> 17) & 255) << 2) | ((p >> TSHIFT) & 3);
      int pos = atomicAdd(&cur[key], 1);
      stage[pos] = p & 0x1FFFF;
    }
    __syncthreads();
    for (int i = t; i < cntE; i += 256) adj[seg_base + i] = stage[i];
  } else {
    // fallback (statistically never)
    for (int i = t; i < cntE; i += 256) {
      int p = adjTmp[seg_base + i];
      int key = (((p >> 17) & 255) << 2) | ((p >> TSHIFT) & 3);
      int pos = atomicAdd(&cur[key], 1);
      adj[seg_base + pos] = p & 0x1FFFF;
    }
  }
}

// ---- weight prep: Wt1[64][128] = W1^T bf16, Wt2[32][64] = W2^T bf16 ----
__global__ __launch_bounds__(256) void k_prepW(const float* __restrict__ W1,
                                               const float* __restrict__ W2,
                                               short* __restrict__ Wt1,
                                               short* __restrict__ Wt2) {
  int t = blockIdx.x * 256 + threadIdx.x;
  if (t < 128 * 64) { int k = t >> 6, c = t & 63; Wt1[c * 128 + k] = f2b(W1[t]); }
  if (t < 64 * 32)  { int k = t >> 5, c = t & 31; Wt2[c * 64 + k] = f2b(W2[t]); }
}

// ---- MFMA gemm1: g1[n,64] = dinv[r]*(x[n,128] @ W1[128,64]), bf16 out ----
__global__ __launch_bounds__(256) void k_gemm1(const float* __restrict__ x,
                                               const short* __restrict__ Wt,  // [64][128] bf16
                                               const float* __restrict__ dinv,
                                               bf16* __restrict__ g1, int n) {
  int wave = threadIdx.x >> 6;
  int lane = threadIdx.x & 63;
  int m = lane & 15;
  int quad = lane >> 4;
  int r = blockIdx.x * 64 + wave * 16 + m;

  s8v afr[4];
  if (r < n) {
    const float* ap = x + (size_t)r * 128 + quad * 8;
#pragma unroll
    for (int kc = 0; kc < 4; kc++) {
      float4 u = *(const float4*)(ap + kc * 32);
      float4 v = *(const float4*)(ap + kc * 32 + 4);
      s8v a;
      a[0] = f2b(u.x); a[1] = f2b(u.y); a[2] = f2b(u.z); a[3] = f2b(u.w);
      a[4] = f2b(v.x); a[5] = f2b(v.y); a[6] = f2b(v.z); a[7] = f2b(v.w);
      afr[kc] = a;
    }
  } else {
#pragma unroll
    for (int kc = 0; kc < 4; kc++) afr[kc] = (s8v)(short)0;
  }

  const short* wp = Wt + (size_t)m * 128 + quad * 8;
  s8v bfr[4][4];
#pragma unroll
  for (int nt = 0; nt < 4; nt++)
#pragma unroll
    for (int kc = 0; kc < 4; kc++)
      bfr[nt][kc] = *(const s8v*)(wp + nt * 16 * 128 + kc * 32);

  f4v acc[4] = {f4v{0,0,0,0}, f4v{0,0,0,0}, f4v{0,0,0,0}, f4v{0,0,0,0}};
#pragma unroll
  for (int kc = 0; kc < 4; kc++)
#pragma unroll
    for (int nt = 0; nt < 4; nt++)
      acc[nt] = __builtin_amdgcn_mfma_f32_16x16x32_bf16(afr[kc], bfr[nt][kc], acc[nt], 0, 0, 0);

  int rbase = blockIdx.x * 64 + wave * 16 + quad * 4;
#pragma unroll
  for (int reg = 0; reg < 4; reg++) {
    int rr = rbase + reg;
    if (rr < n) {
      float dv = dinv[rr];
#pragma unroll
      for (int nt = 0; nt < 4; nt++)
        g1[(size_t)rr * 64 + nt * 16 + m] = __float2bfloat16(acc[nt][reg] * dv);
    }
  }
}

// ---- MFMA gemm2: g2[n,32] = dinv[r]*(z1b[n,64] @ W2[64,32]), bf16 out ----
__global__ __launch_bounds__(256) void k_gemm2(const bf16* __restrict__ z1b,
                                               const short* __restrict__ Wt,  // [32][64] bf16
                                               const float* __restrict__ dinv,
                                               short* __restrict__ g2, int n) {
  int wave = threadIdx.x >> 6;
  int lane = threadIdx.x & 63;
  int m = lane & 15;
  int quad = lane >> 4;
  int r = blockIdx.x * 64 + wave * 16 + m;

  s8v afr[2];
  if (r < n) {
    const short* ap = (const short*)z1b + (size_t)r * 64 + quad * 8;
#pragma unroll
    for (int kc = 0; kc < 2; kc++) afr[kc] = *(const s8v*)(ap + kc * 32);
  } else {
#pragma unroll
    for (int kc = 0; kc < 2; kc++) afr[kc] = (s8v)(short)0;
  }

  const short* wp = Wt + (size_t)m * 64 + quad * 8;
  s8v bfr[2][2];
#pragma unroll
  for (int nt = 0; nt < 2; nt++)
#pragma unroll
    for (int kc = 0; kc < 2; kc++)
      bfr[nt][kc] = *(const s8v*)(wp + nt * 16 * 64 + kc * 32);

  f4v acc[2] = {f4v{0,0,0,0}, f4v{0,0,0,0}};
#pragma unroll
  for (int kc = 0; kc < 2; kc++)
#pragma unroll
    for (int nt = 0; nt < 2; nt++)
      acc[nt] = __builtin_amdgcn_mfma_f32_16x16x32_bf16(afr[kc], bfr[nt][kc], acc[nt], 0, 0, 0);

  int rbase = blockIdx.x * 64 + wave * 16 + quad * 4;
#pragma unroll
  for (int reg = 0; reg < 4; reg++) {
    int rr = rbase + reg;
    if (rr < n) {
      float dv = dinv[rr];
#pragma unroll
      for (int nt = 0; nt < 2; nt++)
        g2[(size_t)rr * 32 + nt * 16 + m] = f2b(acc[nt][reg] * dv);
    }
  }
}

// ---- layer-1 aggregate: 1 wave/dest, 8 lanes x 16B per edge (8 edges/inst) ----
// (round-9 body — measured best; explicit prefetch regressed in r10)
__global__ __launch_bounds__(256) void k_gagg1(const int* __restrict__ row_start,
                                               const int* __restrict__ adj,
                                               const float* __restrict__ dinv,
                                               const short* __restrict__ g,   // g1 bf16 [n][64]
                                               const float* __restrict__ bias,
                                               short* __restrict__ z, int n) {
  int wave = threadIdx.x >> 6;
  int lane = threadIdx.x & 63;
  int grp = lane >> 3;     // 0..7: edge slot
  int fl = lane & 7;       // feature slice: shorts fl*8..fl*8+7 (16 B)
  int c = blockIdx.x * 4 + wave;
  if (c >= n) return;
  int start = row_start[c], end = row_start[c + 1];
  float4 a0 = {0.f,0.f,0.f,0.f}, a1 = {0.f,0.f,0.f,0.f};
  int j = start;
  for (; j + 32 <= end; j += 32) {      // 32 edges (4 KB) in flight per iter
#pragma unroll
    for (int u = 0; u < 4; u++) {
      int r = adj[j + u * 8 + grp];
      int4 pk = *(const int4*)(g + r * 64 + fl * 8);
      bf4_acc(pk.x, pk.y, a0);
      bf4_acc(pk.z, pk.w, a1);
    }
  }
  for (; j < end; j += 8) {
    int e = j + grp;
    if (e < end) {
      int r = adj[e];
      int4 pk = *(const int4*)(g + r * 64 + fl * 8);
      bf4_acc(pk.x, pk.y, a0);
      bf4_acc(pk.z, pk.w, a1);
    }
  }
  // reduce 8 edge slots (lane bits 3..5)
#pragma unroll
  for (int s = 8; s <= 32; s <<= 1) {
    a0.x += __shfl_xor(a0.x, s); a0.y += __shfl_xor(a0.y, s);
    a0.z += __shfl_xor(a0.z, s); a0.w += __shfl_xor(a0.w, s);
    a1.x += __shfl_xor(a1.x, s); a1.y += __shfl_xor(a1.y, s);
    a1.z += __shfl_xor(a1.z, s); a1.w += __shfl_xor(a1.w, s);
  }
  if (grp == 0) {
    int4 pk = *(const int4*)(g + c * 64 + fl * 8);   // self-loop
    bf4_acc(pk.x, pk.y, a0);
    bf4_acc(pk.z, pk.w, a1);
    float d = dinv[c];
    float4 b0 = *(const float4*)(bias + fl * 8);
    float4 b1 = *(const float4*)(bias + fl * 8 + 4);
    float v0 = fmaxf(fmaf(d, a0.x, b0.x), 0.f);
    float v1 = fmaxf(fmaf(d, a0.y, b0.y), 0.f);
    float v2 = fmaxf(fmaf(d, a0.z, b0.z), 0.f);
    float v3 = fmaxf(fmaf(d, a0.w, b0.w), 0.f);
    float v4 = fmaxf(fmaf(d, a1.x, b1.x), 0.f);
    float v5 = fmaxf(fmaf(d, a1.y, b1.y), 0.f);
    float v6 = fmaxf(fmaf(d, a1.z, b1.z), 0.f);
    float v7 = fmaxf(fmaf(d, a1.w, b1.w), 0.f);
    int4 out;
    out.x = (int)(unsigned short)f2b(v0) | ((int)f2b(v1) << 16);
    out.y = (int)(unsigned short)f2b(v2) | ((int)f2b(v3) << 16);
    out.z = (int)(unsigned short)f2b(v4) | ((int)f2b(v5) << 16);
    out.w = (int)(unsigned short)f2b(v6) | ((int)f2b(v7) << 16);
    *(int4*)(z + c * 64 + fl * 8) = out;
  }
}

// ---- layer-2 aggregate: 1 wave/dest, 4 lanes x 16B per edge (16 edges/inst) ----
// (round-9 body)
__global__ __launch_bounds__(256) void k_gagg2(const int* __restrict__ row_start,
                                               const int* __restrict__ adj,
                                               const float* __restrict__ dinv,
                                               const short* __restrict__ g,   // g2 bf16 [n][32]
                                               const float* __restrict__ bias,
                                               float* __restrict__ z, int n) {
  int wave = threadIdx.x >> 6;
  int lane = threadIdx.x & 63;
  int grp = lane >> 2;     // 0..15: edge slot
  int fl = lane & 3;       // feature slice: shorts fl*8..fl*8+7 (16 B)
  int c = blockIdx.x * 4 + wave;
  if (c >= n) return;
  int start = row_start[c], end = row_start[c + 1];
  float4 a0 = {0.f,0.f,0.f,0.f}, a1 = {0.f,0.f,0.f,0.f};
  int j = start;
  for (; j + 32 <= end; j += 32) {      // 32 edges (2 KB) in flight per iter
#pragma unroll
    for (int u = 0; u < 2; u++) {
      int r = adj[j + u * 16 + grp];
      int4 pk = *(const int4*)(g + r * 32 + fl * 8);
      bf4_acc(pk.x, pk.y, a0);
      bf4_acc(pk.z, pk.w, a1);
    }
  }
  for (; j < end; j += 16) {
    int e = j + grp;
    if (e < end) {
      int r = adj[e];
      int4 pk = *(const int4*)(g + r * 32 + fl * 8);
      bf4_acc(pk.x, pk.y, a0);
      bf4_acc(pk.z, pk.w, a1);
    }
  }
  // reduce 16 edge slots (lane bits 2..5)
#pragma unroll
  for (int s = 4; s <= 32; s <<= 1) {
    a0.x += __shfl_xor(a0.x, s); a0.y += __shfl_xor(a0.y, s);
    a0.z += __shfl_xor(a0.z, s); a0.w += __shfl_xor(a0.w, s);
    a1.x += __shfl_xor(a1.x, s); a1.y += __shfl_xor(a1.y, s);
    a1.z += __shfl_xor(a1.z, s); a1.w += __shfl_xor(a1.w, s);
  }
  if (grp == 0) {
    int4 pk = *(const int4*)(g + c * 32 + fl * 8);   // self-loop
    bf4_acc(pk.x, pk.y, a0);
    bf4_acc(pk.z, pk.w, a1);
    float d = dinv[c];
    float4 b0 = *(const float4*)(bias + fl * 8);
    float4 b1 = *(const float4*)(bias + fl * 8 + 4);
    float4 o0, o1;
    o0.x = fmaf(d, a0.x, b0.x); o0.y = fmaf(d, a0.y, b0.y);
    o0.z = fmaf(d, a0.z, b0.z); o0.w = fmaf(d, a0.w, b0.w);
    o1.x = fmaf(d, a1.x, b1.x); o1.y = fmaf(d, a1.y, b1.y);
    o1.z = fmaf(d, a1.z, b1.z); o1.w = fmaf(d, a1.w, b1.w);
    *(float4*)(z + c * 32 + fl * 8) = o0;
    *(float4*)(z + c * 32 + fl * 8 + 4) = o1;
  }
}

// ---- link decode: half-wave per label edge, shuffle reduce, fp32 out ----
__global__ __launch_bounds__(256) void k_decode(const int* __restrict__ ea,
                                                const int* __restrict__ eb,
                                                const float* __restrict__ z2,
                                                float* __restrict__ out, int EL) {
  int lane = threadIdx.x & 31;
  int e = blockIdx.x * 8 + (threadIdx.x >> 5);
  if (e >= EL) return;
  int a = ea[e], b = eb[e];
  float p = z2[a * 32 + lane] * z2[b * 32 + lane];
  p += __shfl_down(p, 16);
  p += __shfl_down(p, 8);
  p += __shfl_down(p, 4);
  p += __shfl_down(p, 2);
  p += __shfl_down(p, 1);
  if (lane == 0) out[e] = p;
}

extern "C" void kernel_launch(void* const* d_in, const int* in_sizes, int n_in,
                              void* d_out, int out_size, void* d_ws, size_t ws_size,
                              hipStream_t stream) {
  const float* x   = (const float*)d_in[0];
  const float* W1  = (const float*)d_in[1];
  const float* b1  = (const float*)d_in[2];
  const float* W2  = (const float*)d_in[3];
  const float* b2  = (const float*)d_in[4];
  const int*   ei  = (const int*)d_in[5];   // [2,E]: row=ei[0..E), col=ei[E..2E)
  const int*   eli = (const int*)d_in[6];   // [2,EL]

  const int N  = in_sizes[0] / 128;  // 100000
  const int E  = in_sizes[5] / 2;    // 3200000
  const int EL = in_sizes[6] / 2;    // 200000
  const int* row = ei;
  const int* col = ei + E;
  const int NBUCK = (N + BNODES - 1) / BNODES;   // 391
  const int NCHNK = (E + CHUNK - 1) / CHUNK;     // 782

  // workspace (~60 MB)
  char* ws = (char*)d_ws;
  size_t off = 0;
  auto take = [&](size_t bytes) { char* p = ws + off; off += (bytes + 255) & ~(size_t)255; return p; };
  float* dinv      = (float*)take((size_t)N * 4);
  int*   row_start = (int*)take((size_t)(N + 1) * 4);
  int*   btot      = (int*)take((size_t)NBUCK * 4);
  int*   bbase     = (int*)take((size_t)(NBUCK + 1) * 4);
  short* Wt1       = (short*)take((size_t)64 * 128 * 2);
  short* Wt2       = (short*)take((size_t)32 * 64 * 2);
  int*   chist     = (int*)take((size_t)NCHNK * NBUCK * 4);   // 1.22 MB
  int*   adjTmp    = (int*)take((size_t)E * 4);               // 12.8 MB
  int*   adj       = (int*)take((size_t)E * 4);               // 12.8 MB
  char*  bufH      = take((size_t)N * 64 * 2);                // g1 bf16 / g2 bf16
  short* z1b       = (short*)take((size_t)N * 64 * 2);        // relu'd, bf16
  float* z2        = (float*)take((size_t)N * 32 * 4);
  (void)ws_size; (void)n_in; (void)out_size;

  bf16*  g1 = (bf16*)bufH;
  short* g2 = (short*)bufH;   // aliases g1 (g1 dead when g2 written)

  k_prepW     <<<32, 256, 0, stream>>>(W1, W2, Wt1, Wt2);
  k_hist      <<<NCHNK, 256, 0, stream>>>(col, E, NBUCK, chist);
  k_scanbuck  <<<NBUCK, 256, 0, stream>>>(chist, NCHNK, NBUCK, btot);
  k_scanbase  <<<1, 512, 0, stream>>>(btot, NBUCK, bbase, row_start, N);
  k_binpass   <<<NCHNK, 256, 0, stream>>>(row, col, E, NBUCK, bbase, chist, adjTmp);
  k_bucketsort<<<NBUCK, 256, 0, stream>>>(bbase, adjTmp, adj, row_start, dinv, N);

  k_gemm1<<<(N + 63) / 64, 256, 0, stream>>>(x, Wt1, dinv, g1, N);
  k_gagg1<<<(N + 3) / 4, 256, 0, stream>>>(row_start, adj, dinv, (const short*)g1, b1, z1b, N);

  k_gemm2<<<(N + 63) / 64, 256, 0, stream>>>((const bf16*)z1b, Wt2, dinv, g2, N);
  k_gagg2<<<(N + 3) / 4, 256, 0, stream>>>(row_start, adj, dinv, g2, b2, z2, N);

  k_decode<<<(EL + 7) / 8, 256, 0, stream>>>(eli, eli + EL, z2, (float*)d_out, EL);
}